// Round 8
// baseline (874.838 us; speedup 1.0000x reference)
//
#include <hip/hip_runtime.h>

typedef short bf16x8 __attribute__((ext_vector_type(8)));
typedef float f32x4  __attribute__((ext_vector_type(4)));

#define EPSF 1e-5f

// ---------------- workspace layout (float element offsets) — EXACT round-5 ----------------
#define OFF_P0   0          // 4,915,200 (conv ping)
#define OFF_U    1048576    //   409,600 (in P0 tail; conv3 out = 307,200 -> no overlap)
#define OFF_V    1572864    //   409,600
#define OFF_P1   4915200    // 1,228,800 (conv pong)
#define OFF_SS   6144000    // 384
#define OFF_SACC 6144384    // 96 (+pad)
#define OFF_Q    6144512    // 16,384
#define OFF_WP   6160896    // 196,608 float-slots: WP_hi + WP_lo bf16 frags
#define OFF_W1UV 6357504    // 13,312  (52 x 256)
#define OFF_W1Q  6370816    // 166,400 (650 x 256)
#define OFF_FW1T 6537216    // 65,536
#define OFF_FC2T 6602752    // 65,536
#define OFF_FC3T 6668288    // 32,768
#define OFF_XG   6701056    // 16,384
// end: 6,717,440 floats = 25.6 MiB

__device__ __forceinline__ unsigned short f2bf(float f) {
    union { float f; unsigned u; } cv; cv.f = f;
    const unsigned u = cv.u;
    return (unsigned short)((u + 0x7fffu + ((u >> 16) & 1u)) >> 16);  // RNE
}
__device__ __forceinline__ float bf2f(unsigned short h) {
    union { unsigned u; float f; } cv; cv.u = (unsigned)h << 16; return cv.f;
}

// ---------------- prep: zero + weight repacks (hi/lo split) — EXACT round-5 ----------------
__global__ __launch_bounds__(256) void k_prep(
    const float* __restrict__ gw1, const float* __restrict__ gw234,
    const float* __restrict__ fw1, const float* __restrict__ fc2w,
    const float* __restrict__ fc3w, float* __restrict__ ws)
{
    int idx = blockIdx.x * 256 + threadIdx.x;
    if (idx < 16384) { ws[OFF_XG + idx] = 0.f; return; }
    idx -= 16384;
    if (idx < 96) { ws[OFF_SACC + idx] = 0.f; return; }
    idx -= 96;
    if (idx < 49152) {
        const int isLo = idx >= 24576;
        const int f = isLo ? idx - 24576 : idx;
        const int lane = f & 63;
        const int nt = (f >> 6) & 15;
        const int kb = (f >> 10) & 7;
        const int l  = f >> 13;
        const int o = nt * 16 + (lane & 15);
        const int k = kb * 32 + (lane >> 4) * 8;
        const float* src = gw234 + ((size_t)l * 256 + o) * 256 + k;
        unsigned short* dst = (unsigned short*)(ws + OFF_WP) + (size_t)idx * 8;
        #pragma unroll
        for (int j = 0; j < 8; ++j) {
            const float x = src[j];
            const unsigned short hi = f2bf(x);
            dst[j] = isLo ? f2bf(x - bf2f(hi)) : hi;
        }
        return;
    }
    idx -= 49152;
    if (idx < 13312) {
        const int o = idx & 255, k = idx >> 8;
        ws[OFF_W1UV + idx] = gw1[(size_t)o * 702 + k];
        return;
    }
    idx -= 13312;
    if (idx < 166400) {
        const int o = idx & 255, k = idx >> 8;
        ws[OFF_W1Q + idx] = gw1[(size_t)o * 702 + 52 + k];
        return;
    }
    idx -= 166400;
    if (idx < 65536) { const int o = idx & 255, k = idx >> 8; ws[OFF_FW1T + idx] = fw1[o * 256 + k];  return; }
    idx -= 65536;
    if (idx < 65536) { const int o = idx & 255, k = idx >> 8; ws[OFF_FC2T + idx] = fc2w[o * 256 + k]; return; }
    idx -= 65536;
    if (idx < 32768) { const int o = idx & 127, k = idx >> 7; ws[OFF_FC3T + idx] = fc3w[o * 256 + k]; return; }
}

// ---------------- conv layer 1 (round-5 mapping + interior fast path) ----------------
__global__ __launch_bounds__(256) void k_conv_first(
    const float* __restrict__ img, const float* __restrict__ img2,
    const float* __restrict__ w, const float* __restrict__ bias,
    float* __restrict__ out)
{
    const int idx = blockIdx.x * 256 + threadIdx.x;
    if (idx >= 128*24*40*40) return;
    const int wo = idx % 40;
    const int ho = (idx / 40) % 40;
    const int co = (idx / 1600) % 24;
    const int b  = idx / (1600*24);
    const float* in = (b < 64 ? img : img2) + (size_t)(b & 63) * 3 * 6400;
    float s = bias[co];
    if (ho >= 1 && wo >= 1) {
        // interior: 2*ho-1 >= 1, 2*ho+1 <= 79 (IH=80=2*OH) — all 9 taps in-bounds
        const float* p0 = in + (2*ho - 1)*80 + (2*wo - 1);
        #pragma unroll
        for (int ci = 0; ci < 3; ++ci) {
            const float* p  = p0 + (size_t)ci * 6400;
            const float* wp = w + (co*3 + ci) * 9;
            s += p[0]  *wp[0] + p[1]  *wp[1] + p[2]  *wp[2]
               + p[80] *wp[3] + p[81] *wp[4] + p[82] *wp[5]
               + p[160]*wp[6] + p[161]*wp[7] + p[162]*wp[8];
        }
    } else {
        for (int ci = 0; ci < 3; ++ci) {
            const float* ip = in + (size_t)ci * 6400;
            const float* wp = w + (co*3 + ci) * 9;
            #pragma unroll
            for (int kh = 0; kh < 3; ++kh) {
                const int ih = 2*ho - 1 + kh;
                if (ih < 0 || ih >= 80) continue;
                #pragma unroll
                for (int kw = 0; kw < 3; ++kw) {
                    const int iw = 2*wo - 1 + kw;
                    if (iw < 0 || iw >= 80) continue;
                    s += ip[ih*80 + iw] * wp[kh*3 + kw];
                }
            }
        }
    }
    out[idx] = fmaxf(s, 0.f);
}

// ---------------- conv layers 2-4 (round-5 mapping + interior fast path) ----------------
__global__ __launch_bounds__(256) void k_conv(
    const float* __restrict__ in, const float* __restrict__ ss,
    const float* __restrict__ w, const float* __restrict__ bias,
    float* __restrict__ out, int IH, int IW, int OH, int OW)
{
    const int idx = blockIdx.x * 256 + threadIdx.x;
    const int total = 128*24*OH*OW;
    if (idx >= total) return;
    const int wo = idx % OW;
    const int ho = (idx / OW) % OH;
    const int co = (idx / (OW*OH)) % 24;
    const int b  = idx / (OW*OH*24);
    const float* sc = ss + (b >> 6) * 48;
    float s = bias[co];
    if (ho >= 1 && wo >= 1) {
        // interior: all 9 taps in-bounds (upper bound never trips: 2*ho+1 <= IH-1)
        const float* p0 = in + ((size_t)(b*24))*IH*IW + (2*ho - 1)*IW + (2*wo - 1);
        #pragma unroll 4
        for (int ci = 0; ci < 24; ++ci) {
            const float scale = sc[ci], shift = sc[24 + ci];
            const float* p  = p0 + (size_t)ci * IH * IW;
            const float* wp = w + (co*24 + ci) * 9;
            const float w0 = wp[0], w1 = wp[1], w2 = wp[2];
            const float w3 = wp[3], w4 = wp[4], w5 = wp[5];
            const float w6 = wp[6], w7 = wp[7], w8 = wp[8];
            const float dot = p[0]     *w0 + p[1]     *w1 + p[2]     *w2
                            + p[IW]    *w3 + p[IW+1]  *w4 + p[IW+2]  *w5
                            + p[2*IW]  *w6 + p[2*IW+1]*w7 + p[2*IW+2]*w8;
            const float wsum = w0+w1+w2+w3+w4+w5+w6+w7+w8;
            s += dot * scale + shift * wsum;   // Σ((x*sc+sh)*w) — valid: no padded taps
        }
    } else {
        for (int ci = 0; ci < 24; ++ci) {
            const float scale = sc[ci], shift = sc[24 + ci];
            const float* ip = in + (size_t)(b*24 + ci) * IH * IW;
            const float* wp = w + (co*24 + ci) * 9;
            #pragma unroll
            for (int kh = 0; kh < 3; ++kh) {
                const int ih = 2*ho - 1 + kh;
                if (ih < 0 || ih >= IH) continue;
                #pragma unroll
                for (int kw = 0; kw < 3; ++kw) {
                    const int iw = 2*wo - 1 + kw;
                    if (iw < 0 || iw >= IW) continue;
                    s += (ip[ih*IW + iw] * scale + shift) * wp[kh*3 + kw];
                }
            }
        }
    }
    out[idx] = fmaxf(s, 0.f);
}

// ---------------- split-k BN stats (layer 1) — EXACT round-5 ----------------
__global__ __launch_bounds__(256) void k_stats_part(
    const float* __restrict__ y, float* __restrict__ sacc, int HW)
{
    const int img = blockIdx.x / (24*8);
    const int c   = (blockIdx.x / 8) % 24;
    const int sp  = blockIdx.x % 8;
    const int N = 64 * HW, chunk = N / 8;
    float sum = 0.f, sq = 0.f;
    for (int i = sp*chunk + threadIdx.x; i < (sp+1)*chunk; i += 256) {
        const int bb = i / HW, j = i - bb*HW;
        const float v = y[(size_t)((img*64 + bb)*24 + c) * HW + j];
        sum += v; sq += v*v;
    }
    #pragma unroll
    for (int off = 32; off > 0; off >>= 1) {
        sum += __shfl_down(sum, off);
        sq  += __shfl_down(sq, off);
    }
    __shared__ float red[8];
    const int lane = threadIdx.x & 63, wid = threadIdx.x >> 6;
    if (lane == 0) { red[wid] = sum; red[4 + wid] = sq; }
    __syncthreads();
    if (threadIdx.x == 0) {
        atomicAdd(&sacc[img*24 + c],      red[0]+red[1]+red[2]+red[3]);
        atomicAdd(&sacc[48 + img*24 + c], red[4]+red[5]+red[6]+red[7]);
    }
}

__global__ void k_stats_fin(const float* __restrict__ sacc, const float* __restrict__ g,
                            const float* __restrict__ beta, float* __restrict__ ss, int HW)
{
    const int t = threadIdx.x;
    if (t >= 48) return;
    const int img = t / 24, c = t % 24;
    const float N = 64.f * (float)HW;
    const float mean = sacc[t] / N;
    const float var  = sacc[48 + t] / N - mean*mean;
    const float scale = g[c] * rsqrtf(var + EPSF);
    ss[img*48 + c]      = scale;
    ss[img*48 + 24 + c] = beta[c] - mean * scale;
}

// ---------------- single-pass BN stats (layers 2-4) — EXACT round-5 ----------------
__global__ __launch_bounds__(256) void k_stats(
    const float* __restrict__ y, const float* __restrict__ g, const float* __restrict__ beta,
    float* __restrict__ ss, int HW)
{
    const int img = blockIdx.x / 24, c = blockIdx.x % 24;
    const int N = 64 * HW;
    float sum = 0.f, sq = 0.f;
    for (int i = threadIdx.x; i < N; i += 256) {
        const int bb = i / HW, j = i - bb*HW;
        const float v = y[(size_t)((img*64 + bb)*24 + c) * HW + j];
        sum += v; sq += v*v;
    }
    #pragma unroll
    for (int off = 32; off > 0; off >>= 1) {
        sum += __shfl_down(sum, off);
        sq  += __shfl_down(sq, off);
    }
    __shared__ float red[8];
    const int lane = threadIdx.x & 63, wid = threadIdx.x >> 6;
    if (lane == 0) { red[wid] = sum; red[4 + wid] = sq; }
    __syncthreads();
    if (threadIdx.x == 0) {
        const float S  = red[0]+red[1]+red[2]+red[3];
        const float Q2 = red[4]+red[5]+red[6]+red[7];
        const float mean = S / (float)N;
        const float var  = Q2 / (float)N - mean*mean;
        const float scale = g[c] * rsqrtf(var + EPSF);
        ss[img*48 + c]      = scale;
        ss[img*48 + 24 + c] = beta[c] - mean * scale;
    }
}

// ---------------- U,V — EXACT round-5 ----------------
__global__ __launch_bounds__(256) void k_uv(
    const float* __restrict__ P1, const float* __restrict__ SS4,
    const float* __restrict__ w1uvT, float* __restrict__ Ub, float* __restrict__ Vb)
{
    __shared__ float f[26];
    const int row = blockIdx.x;           // b*25+cell, b<64 (img1)
    const int b = row / 25, cell = row % 25;
    const int t = threadIdx.x;
    if (t < 26) {
        float v;
        if (t < 24)      v = P1[((size_t)(b*24 + t))*25 + cell] * SS4[t] + SS4[24 + t];
        else if (t == 24) v = ((float)cell / 5.f - 2.f) * 0.5f;
        else              v = ((float)(cell % 5) - 2.f) * 0.5f;
        f[t] = v;
    }
    __syncthreads();
    float su = 0.f, sv = 0.f;
    #pragma unroll
    for (int k = 0; k < 26; ++k) {
        su += f[k] * w1uvT[k*256 + t];
        sv += f[k] * w1uvT[(26 + k)*256 + t];
    }
    Ub[(size_t)row*256 + t] = su;
    Vb[(size_t)row*256 + t] = sv;
}

// ---------------- Q — EXACT round-5 ----------------
__global__ __launch_bounds__(256) void k_q(
    const float* __restrict__ P1, const float* __restrict__ SS4,
    const float* __restrict__ w1qT, const float* __restrict__ gb, float* __restrict__ Qb)
{
    __shared__ float f[650];
    const int b = blockIdx.x, t = threadIdx.x;
    for (int i = t; i < 650; i += 256) {
        const int cell = i / 26, ff = i % 26;
        float v;
        if (ff < 24)      v = P1[((size_t)((64 + b)*24 + ff))*25 + cell] * SS4[48 + ff] + SS4[72 + ff];
        else if (ff == 24) v = ((float)cell / 5.f - 2.f) * 0.5f;
        else               v = ((float)(cell % 5) - 2.f) * 0.5f;
        f[i] = v;
    }
    __syncthreads();
    float s = gb[t];
    #pragma unroll 2
    for (int k = 0; k < 650; ++k) s += f[k] * w1qT[k*256 + t];
    Qb[b*256 + t] = s;
}

// ---------------- MFMA g-MLP (bf16x3) + sum pool — EXACT round-5 ----------------
__global__ __launch_bounds__(256) void k_gmlp(
    const float* __restrict__ U, const float* __restrict__ V, const float* __restrict__ Q,
    const unsigned short* __restrict__ WP, const float* __restrict__ gb, float* __restrict__ xg)
{
    __shared__ unsigned short hhi[16384];   // 64x256 bf16 = 32 KB
    __shared__ unsigned short hlo[16384];
    const int b    = blockIdx.x / 10;
    const int row0 = (blockIdx.x % 10) * 64;
    const int tid  = threadIdx.x;
    const int lane = tid & 63, w = tid >> 6;
    const int r0 = w * 16;

    {
        const float2* Q2 = (const float2*)(Q + b*256);
        const float2 q0 = Q2[lane], q1 = Q2[64 + lane];
        for (int rr = 0; rr < 16; ++rr) {
            const int row = r0 + rr;
            int p = row0 + row; if (p > 624) p = 624;
            const float2* u2p = (const float2*)(U + ((size_t)(b*25 + p % 25)) * 256);
            const float2* v2p = (const float2*)(V + ((size_t)(b*25 + p / 25)) * 256);
            #pragma unroll
            for (int cc = 0; cc < 2; ++cc) {
                const int cp = cc*64 + lane;
                const float2 u2 = u2p[cp], v2 = v2p[cp];
                const float2 q2 = cc ? q1 : q0;
                const float x0 = fmaxf(u2.x + v2.x + q2.x, 0.f);
                const float x1 = fmaxf(u2.y + v2.y + q2.y, 0.f);
                const unsigned short h0 = f2bf(x0), h1 = f2bf(x1);
                const float l0 = x0 - bf2f(h0), l1 = x1 - bf2f(h1);
                const int byte = (row*512 + cp*4) ^ ((row & 7) << 4);
                *(unsigned*)((char*)hhi + byte) = (unsigned)h0 | ((unsigned)h1 << 16);
                *(unsigned*)((char*)hlo + byte) = (unsigned)f2bf(l0) | ((unsigned)f2bf(l1) << 16);
            }
        }
    }
    __syncthreads();

    f32x4 acc[16];
    #pragma unroll 1
    for (int l = 0; l < 3; ++l) {
        #pragma unroll
        for (int nt = 0; nt < 16; ++nt) acc[nt] = (f32x4)0.f;
        const int ar = r0 + (lane & 15);
        #pragma unroll 1
        for (int kb = 0; kb < 8; ++kb) {
            const int off = (ar*512 + kb*64 + (lane >> 4)*16) ^ ((ar & 7) << 4);
            const bf16x8 ahi = *(const bf16x8*)((char*)hhi + off);
            const bf16x8 alo = *(const bf16x8*)((char*)hlo + off);
            const bf16x8* whi = (const bf16x8*)WP + ((size_t)(l*8 + kb)*16)*64 + lane;
            const bf16x8* wlo = whi + 24576;
            #pragma unroll
            for (int nt = 0; nt < 16; ++nt) {
                const bf16x8 bh = whi[nt*64];
                const bf16x8 bl = wlo[nt*64];
                acc[nt] = __builtin_amdgcn_mfma_f32_16x16x32_bf16(ahi, bh, acc[nt], 0, 0, 0);
                acc[nt] = __builtin_amdgcn_mfma_f32_16x16x32_bf16(ahi, bl, acc[nt], 0, 0, 0);
                acc[nt] = __builtin_amdgcn_mfma_f32_16x16x32_bf16(alo, bh, acc[nt], 0, 0, 0);
            }
        }
        __syncthreads();
        if (l < 2) {
            #pragma unroll
            for (int nt = 0; nt < 16; ++nt) {
                const int col = nt*16 + (lane & 15);
                const float bias = gb[(l+1)*256 + col];
                #pragma unroll
                for (int r = 0; r < 4; ++r) {
                    const int row = r0 + 4*(lane >> 4) + r;
                    const float v = fmaxf(acc[nt][r] + bias, 0.f);
                    const unsigned short hv = f2bf(v);
                    const float lv = v - bf2f(hv);
                    const int byte = (row*512 + col*2) ^ ((row & 7) << 4);
                    *(unsigned short*)((char*)hhi + byte) = hv;
                    *(unsigned short*)((char*)hlo + byte) = f2bf(lv);
                }
            }
            __syncthreads();
        } else {
            #pragma unroll
            for (int nt = 0; nt < 16; ++nt) {
                const int col = nt*16 + (lane & 15);
                const float bias = gb[3*256 + col];
                float s = 0.f;
                #pragma unroll
                for (int r = 0; r < 4; ++r) {
                    const int row = r0 + 4*(lane >> 4) + r;
                    if (row0 + row < 625) s += fmaxf(acc[nt][r] + bias, 0.f);
                }
                s += __shfl_xor(s, 16);
                s += __shfl_xor(s, 32);
                if (lane < 16) atomicAdd(&xg[b*256 + col], s);
            }
        }
    }
}

// ---------------- fused head — EXACT round-5 ----------------
__global__ __launch_bounds__(256) void k_head(
    const float* __restrict__ XG, const float* __restrict__ fw1T, const float* __restrict__ fb1,
    const float* __restrict__ fc2T, const float* __restrict__ fc2b,
    const float* __restrict__ fc3T, const float* __restrict__ fc3b, float* __restrict__ out)
{
    __shared__ float xa[256], xb[256], ys[128];
    const int b = blockIdx.x, t = threadIdx.x;
    xa[t] = XG[b*256 + t];
    __syncthreads();
    float s = fb1[t];
    #pragma unroll 4
    for (int k = 0; k < 256; ++k) s += xa[k] * fw1T[k*256 + t];
    xb[t] = fmaxf(s, 0.f);
    __syncthreads();
    s = fc2b[t];
    #pragma unroll 4
    for (int k = 0; k < 256; ++k) s += xb[k] * fc2T[k*256 + t];
    xa[t] = fmaxf(s, 0.f);
    __syncthreads();
    if (t < 128) {
        s = fc3b[t];
        #pragma unroll 4
        for (int k = 0; k < 256; ++k) s += xa[k] * fc3T[k*128 + t];
        ys[t] = s;
    }
    __syncthreads();
    if (t < 16) {
        float m = ys[t*8];
        #pragma unroll
        for (int i = 1; i < 8; ++i) m = fmaxf(m, ys[t*8 + i]);
        float e[8], sum = 0.f;
        #pragma unroll
        for (int i = 0; i < 8; ++i) { e[i] = expf(ys[t*8 + i] - m); sum += e[i]; }
        const float inv = 1.f / sum;
        #pragma unroll
        for (int i = 0; i < 8; ++i) out[b*128 + t*8 + i] = fmaxf(e[i]*inv, 0.001f);
    }
}

extern "C" void kernel_launch(void* const* d_in, const int* in_sizes, int n_in,
                              void* d_out, int out_size, void* d_ws, size_t ws_size,
                              hipStream_t stream)
{
    const float* img   = (const float*)d_in[0];
    const float* img2  = (const float*)d_in[1];
    const float* cw1   = (const float*)d_in[2];
    const float* cw234 = (const float*)d_in[3];
    const float* cb    = (const float*)d_in[4];
    const float* bng   = (const float*)d_in[5];
    const float* bnb   = (const float*)d_in[6];
    const float* gw1   = (const float*)d_in[7];
    const float* gw234 = (const float*)d_in[8];
    const float* gb    = (const float*)d_in[9];
    const float* fw1   = (const float*)d_in[10];
    const float* fb1   = (const float*)d_in[11];
    const float* fc2w  = (const float*)d_in[12];
    const float* fc2b  = (const float*)d_in[13];
    const float* fc3w  = (const float*)d_in[14];
    const float* fc3b  = (const float*)d_in[15];

    float* ws = (float*)d_ws;
    float* P0 = ws + OFF_P0;  float* P1 = ws + OFF_P1;   float* SS  = ws + OFF_SS;
    float* SA = ws + OFF_SACC; float* Ub = ws + OFF_U;   float* Vb  = ws + OFF_V;
    float* Qb = ws + OFF_Q;
    unsigned short* WP = (unsigned short*)(ws + OFF_WP);
    float* W1UV = ws + OFF_W1UV; float* W1Q = ws + OFF_W1Q;
    float* FW1T = ws + OFF_FW1T; float* FC2T = ws + OFF_FC2T; float* FC3T = ws + OFF_FC3T;
    float* XG = ws + OFF_XG;
    float* out = (float*)d_out;

    hipLaunchKernelGGL(k_prep, dim3(1599), dim3(256), 0, stream, gw1, gw234, fw1, fc2w, fc3w, ws);

    hipLaunchKernelGGL(k_conv_first, dim3(19200), dim3(256), 0, stream, img, img2, cw1, cb, P0);
    hipLaunchKernelGGL(k_stats_part, dim3(384), dim3(256), 0, stream, P0, SA, 1600);
    hipLaunchKernelGGL(k_stats_fin,  dim3(1),   dim3(64),  0, stream, SA, bng, bnb, SS, 1600);
    hipLaunchKernelGGL(k_conv,  dim3(4800), dim3(256), 0, stream, P0, SS,      cw234,       cb+24, P1, 40,40,20,20);
    hipLaunchKernelGGL(k_stats, dim3(48),   dim3(256), 0, stream, P1, bng+24, bnb+24, SS+96,  400);
    hipLaunchKernelGGL(k_conv,  dim3(1200), dim3(256), 0, stream, P1, SS+96,   cw234+5184,  cb+48, P0, 20,20,10,10);
    hipLaunchKernelGGL(k_stats, dim3(48),   dim3(256), 0, stream, P0, bng+48, bnb+48, SS+192, 100);
    hipLaunchKernelGGL(k_conv,  dim3(300),  dim3(256), 0, stream, P0, SS+192,  cw234+10368, cb+72, P1, 10,10,5,5);
    hipLaunchKernelGGL(k_stats, dim3(48),   dim3(256), 0, stream, P1, bng+72, bnb+72, SS+288, 25);

    hipLaunchKernelGGL(k_uv, dim3(1600), dim3(256), 0, stream, P1, SS+288, W1UV, Ub, Vb);
    hipLaunchKernelGGL(k_q,  dim3(64),   dim3(256), 0, stream, P1, SS+288, W1Q, gb, Qb);

    hipLaunchKernelGGL(k_gmlp, dim3(640), dim3(256), 0, stream, Ub, Vb, Qb, WP, gb, XG);

    hipLaunchKernelGGL(k_head, dim3(64), dim3(256), 0, stream,
                       XG, FW1T, fb1, FC2T, fc2b, FC3T, fc3b, out);
}

// Round 9
// 600.294 us; speedup vs baseline: 1.4573x; 1.4573x over previous
//
#include <hip/hip_runtime.h>

typedef short bf16x8 __attribute__((ext_vector_type(8)));
typedef float f32x4  __attribute__((ext_vector_type(4)));

#define EPSF 1e-5f

// ---------------- workspace layout (float element offsets) — EXACT round-5/8 ----------------
#define OFF_P0   0          // 4,915,200 (conv ping)
#define OFF_U    1048576    //   409,600 (in P0 tail; conv3 out = 307,200 -> no overlap)
#define OFF_V    1572864    //   409,600
#define OFF_P1   4915200    // 1,228,800 (conv pong)
#define OFF_SS   6144000    // 384
#define OFF_SACC 6144384    // 96 (+pad)
#define OFF_Q    6144512    // 16,384
#define OFF_WP   6160896    // 196,608 float-slots: WP_hi + WP_lo bf16 frags
#define OFF_W1UV 6357504    // 13,312  (52 x 256)
#define OFF_W1Q  6370816    // 166,400 (650 x 256)
#define OFF_FW1T 6537216    // 65,536
#define OFF_FC2T 6602752    // 65,536
#define OFF_FC3T 6668288    // 32,768
#define OFF_XG   6701056    // 16,384
// end: 6,717,440 floats = 25.6 MiB

__device__ __forceinline__ unsigned short f2bf(float f) {
    union { float f; unsigned u; } cv; cv.f = f;
    const unsigned u = cv.u;
    return (unsigned short)((u + 0x7fffu + ((u >> 16) & 1u)) >> 16);  // RNE
}
__device__ __forceinline__ float bf2f(unsigned short h) {
    union { unsigned u; float f; } cv; cv.u = (unsigned)h << 16; return cv.f;
}

// ---------------- prep: zero + weight repacks (hi/lo split) — EXACT round-5/8 ----------------
__global__ __launch_bounds__(256) void k_prep(
    const float* __restrict__ gw1, const float* __restrict__ gw234,
    const float* __restrict__ fw1, const float* __restrict__ fc2w,
    const float* __restrict__ fc3w, float* __restrict__ ws)
{
    int idx = blockIdx.x * 256 + threadIdx.x;
    if (idx < 16384) { ws[OFF_XG + idx] = 0.f; return; }
    idx -= 16384;
    if (idx < 96) { ws[OFF_SACC + idx] = 0.f; return; }
    idx -= 96;
    if (idx < 49152) {
        const int isLo = idx >= 24576;
        const int f = isLo ? idx - 24576 : idx;
        const int lane = f & 63;
        const int nt = (f >> 6) & 15;
        const int kb = (f >> 10) & 7;
        const int l  = f >> 13;
        const int o = nt * 16 + (lane & 15);
        const int k = kb * 32 + (lane >> 4) * 8;
        const float* src = gw234 + ((size_t)l * 256 + o) * 256 + k;
        unsigned short* dst = (unsigned short*)(ws + OFF_WP) + (size_t)idx * 8;
        #pragma unroll
        for (int j = 0; j < 8; ++j) {
            const float x = src[j];
            const unsigned short hi = f2bf(x);
            dst[j] = isLo ? f2bf(x - bf2f(hi)) : hi;
        }
        return;
    }
    idx -= 49152;
    if (idx < 13312) {
        const int o = idx & 255, k = idx >> 8;
        ws[OFF_W1UV + idx] = gw1[(size_t)o * 702 + k];
        return;
    }
    idx -= 13312;
    if (idx < 166400) {
        const int o = idx & 255, k = idx >> 8;
        ws[OFF_W1Q + idx] = gw1[(size_t)o * 702 + 52 + k];
        return;
    }
    idx -= 166400;
    if (idx < 65536) { const int o = idx & 255, k = idx >> 8; ws[OFF_FW1T + idx] = fw1[o * 256 + k];  return; }
    idx -= 65536;
    if (idx < 65536) { const int o = idx & 255, k = idx >> 8; ws[OFF_FC2T + idx] = fc2w[o * 256 + k]; return; }
    idx -= 65536;
    if (idx < 32768) { const int o = idx & 127, k = idx >> 7; ws[OFF_FC3T + idx] = fc3w[o * 256 + k]; return; }
}

// ---------------- conv layer 1 — EXACT round-8 (interior fast path) ----------------
__global__ __launch_bounds__(256) void k_conv_first(
    const float* __restrict__ img, const float* __restrict__ img2,
    const float* __restrict__ w, const float* __restrict__ bias,
    float* __restrict__ out)
{
    const int idx = blockIdx.x * 256 + threadIdx.x;
    if (idx >= 128*24*40*40) return;
    const int wo = idx % 40;
    const int ho = (idx / 40) % 40;
    const int co = (idx / 1600) % 24;
    const int b  = idx / (1600*24);
    const float* in = (b < 64 ? img : img2) + (size_t)(b & 63) * 3 * 6400;
    float s = bias[co];
    if (ho >= 1 && wo >= 1) {
        const float* p0 = in + (2*ho - 1)*80 + (2*wo - 1);
        #pragma unroll
        for (int ci = 0; ci < 3; ++ci) {
            const float* p  = p0 + (size_t)ci * 6400;
            const float* wp = w + (co*3 + ci) * 9;
            s += p[0]  *wp[0] + p[1]  *wp[1] + p[2]  *wp[2]
               + p[80] *wp[3] + p[81] *wp[4] + p[82] *wp[5]
               + p[160]*wp[6] + p[161]*wp[7] + p[162]*wp[8];
        }
    } else {
        for (int ci = 0; ci < 3; ++ci) {
            const float* ip = in + (size_t)ci * 6400;
            const float* wp = w + (co*3 + ci) * 9;
            #pragma unroll
            for (int kh = 0; kh < 3; ++kh) {
                const int ih = 2*ho - 1 + kh;
                if (ih < 0 || ih >= 80) continue;
                #pragma unroll
                for (int kw = 0; kw < 3; ++kw) {
                    const int iw = 2*wo - 1 + kw;
                    if (iw < 0 || iw >= 80) continue;
                    s += ip[ih*80 + iw] * wp[kh*3 + kw];
                }
            }
        }
    }
    out[idx] = fmaxf(s, 0.f);
}

// ---------------- LDS-tiled conv, layers 2-4 (NON-template; static LDS) ----------------
// Block = (image b, row-tile ty). Stage: (a) weights repacked to lw[(ci*9+tap)*24+co]
// (lanes = consecutive co -> conflict-free), (b) bias, (c) BN-normalized input rows
// [2*oy0-1 .. 2*(oy0+TH)-1] x (IW+2 padded) x 24ch into lin. Work item =
// (co, horizontal output-pixel-pair): per (ci,kh) read 5 input floats (float2+
// float2+scalar, broadcast across the 24-co group) + 3 weights, 12 FMAs.
// Max LDS use: layer2 TH=4 -> 24*9*42 + 5184 + 24 = 14280 floats = 57,120 B.
__global__ __launch_bounds__(256) void k_convL(
    const float* __restrict__ in, const float* __restrict__ ss,
    const float* __restrict__ w, const float* __restrict__ bias,
    float* __restrict__ out, int IH, int IW, int OH, int OW, int TH, int nty)
{
    __shared__ float lds[14280];
    const int NR = 2*TH + 1, CSTR = IW + 2;
    float* lin   = lds;
    float* lw    = lds + 24 * NR * CSTR;
    float* lbias = lw + 5184;

    const int b  = blockIdx.x / nty;
    const int ty = blockIdx.x % nty;
    const int oy0 = ty * TH;
    const int t = threadIdx.x;

    // stage weights: lw[(ci*9+tap)*24+co] = w[(co*24+ci)*9+tap]
    for (int i = t; i < 5184; i += 256) {
        const int co = i % 24, tap = (i / 24) % 9, ci = i / 216;
        lw[i] = w[(co*24 + ci)*9 + tap];
    }
    if (t < 24) lbias[t] = bias[t];

    // stage input (BN-normalized, zero-padded)
    const float* sc = ss + (b >> 6) * 48;
    for (int i = t; i < 24 * NR * CSTR; i += 256) {
        const int ci = i / (NR * CSTR);
        const int r  = i % (NR * CSTR);
        const int y  = r / CSTR, x = r % CSTR;
        const int gy = 2*oy0 - 1 + y, gx = x - 1;
        float v = 0.f;
        if (gy >= 0 && gy < IH && gx >= 0 && gx < IW)
            v = in[(((size_t)b*24 + ci)*IH + gy)*IW + gx] * sc[ci] + sc[24 + ci];
        lin[i] = v;
    }
    __syncthreads();

    const int THe = min(TH, OH - oy0);
    const int PPR = (OW + 1) >> 1;
    const int NWI = THe * PPR * 24;
    for (int wk = t; wk < NWI; wk += 256) {
        const int co = wk % 24;
        const int pr = wk / 24;
        const int i2 = (pr % PPR) * 2;     // first output col of the pair
        const int j  = pr / PPR;           // output row within tile
        const bool hasB = (i2 + 1 < OW);
        float sA = lbias[co], sB = sA;
        const float* wp = lw + co;
        for (int ci = 0; ci < 24; ++ci) {
            const int base = (ci*NR + 2*j)*CSTR + 2*i2;
            const float* wc = wp + ci * 216;
            #pragma unroll
            for (int kh = 0; kh < 3; ++kh) {
                const float* lr = lin + base + kh*CSTR;
                const float2 fa = *(const float2*)lr;         // cols 0,1
                const float2 fb = *(const float2*)(lr + 2);   // cols 2,3
                const float  fc = hasB ? lr[4] : 0.f;         // col 4
                const float w0 = wc[(kh*3 + 0)*24];
                const float w1 = wc[(kh*3 + 1)*24];
                const float w2 = wc[(kh*3 + 2)*24];
                sA += fa.x*w0 + fa.y*w1 + fb.x*w2;
                sB += fb.x*w0 + fb.y*w1 + fc  *w2;
            }
        }
        const size_t o = (((size_t)b*24 + co)*OH + oy0 + j)*OW + i2;
        out[o] = fmaxf(sA, 0.f);
        if (hasB) out[o + 1] = fmaxf(sB, 0.f);
    }
}

// ---------------- split-k BN stats (layer 1) — EXACT round-5/8 ----------------
__global__ __launch_bounds__(256) void k_stats_part(
    const float* __restrict__ y, float* __restrict__ sacc, int HW)
{
    const int img = blockIdx.x / (24*8);
    const int c   = (blockIdx.x / 8) % 24;
    const int sp  = blockIdx.x % 8;
    const int N = 64 * HW, chunk = N / 8;
    float sum = 0.f, sq = 0.f;
    for (int i = sp*chunk + threadIdx.x; i < (sp+1)*chunk; i += 256) {
        const int bb = i / HW, j = i - bb*HW;
        const float v = y[(size_t)((img*64 + bb)*24 + c) * HW + j];
        sum += v; sq += v*v;
    }
    #pragma unroll
    for (int off = 32; off > 0; off >>= 1) {
        sum += __shfl_down(sum, off);
        sq  += __shfl_down(sq, off);
    }
    __shared__ float red[8];
    const int lane = threadIdx.x & 63, wid = threadIdx.x >> 6;
    if (lane == 0) { red[wid] = sum; red[4 + wid] = sq; }
    __syncthreads();
    if (threadIdx.x == 0) {
        atomicAdd(&sacc[img*24 + c],      red[0]+red[1]+red[2]+red[3]);
        atomicAdd(&sacc[48 + img*24 + c], red[4]+red[5]+red[6]+red[7]);
    }
}

__global__ void k_stats_fin(const float* __restrict__ sacc, const float* __restrict__ g,
                            const float* __restrict__ beta, float* __restrict__ ss, int HW)
{
    const int t = threadIdx.x;
    if (t >= 48) return;
    const int img = t / 24, c = t % 24;
    const float N = 64.f * (float)HW;
    const float mean = sacc[t] / N;
    const float var  = sacc[48 + t] / N - mean*mean;
    const float scale = g[c] * rsqrtf(var + EPSF);
    ss[img*48 + c]      = scale;
    ss[img*48 + 24 + c] = beta[c] - mean * scale;
}

// ---------------- single-pass BN stats (layers 2-4) — EXACT round-5/8 ----------------
__global__ __launch_bounds__(256) void k_stats(
    const float* __restrict__ y, const float* __restrict__ g, const float* __restrict__ beta,
    float* __restrict__ ss, int HW)
{
    const int img = blockIdx.x / 24, c = blockIdx.x % 24;
    const int N = 64 * HW;
    float sum = 0.f, sq = 0.f;
    for (int i = threadIdx.x; i < N; i += 256) {
        const int bb = i / HW, j = i - bb*HW;
        const float v = y[(size_t)((img*64 + bb)*24 + c) * HW + j];
        sum += v; sq += v*v;
    }
    #pragma unroll
    for (int off = 32; off > 0; off >>= 1) {
        sum += __shfl_down(sum, off);
        sq  += __shfl_down(sq, off);
    }
    __shared__ float red[8];
    const int lane = threadIdx.x & 63, wid = threadIdx.x >> 6;
    if (lane == 0) { red[wid] = sum; red[4 + wid] = sq; }
    __syncthreads();
    if (threadIdx.x == 0) {
        const float S  = red[0]+red[1]+red[2]+red[3];
        const float Q2 = red[4]+red[5]+red[6]+red[7];
        const float mean = S / (float)N;
        const float var  = Q2 / (float)N - mean*mean;
        const float scale = g[c] * rsqrtf(var + EPSF);
        ss[img*48 + c]      = scale;
        ss[img*48 + 24 + c] = beta[c] - mean * scale;
    }
}

// ---------------- U,V — EXACT round-5/8 ----------------
__global__ __launch_bounds__(256) void k_uv(
    const float* __restrict__ P1, const float* __restrict__ SS4,
    const float* __restrict__ w1uvT, float* __restrict__ Ub, float* __restrict__ Vb)
{
    __shared__ float f[26];
    const int row = blockIdx.x;           // b*25+cell, b<64 (img1)
    const int b = row / 25, cell = row % 25;
    const int t = threadIdx.x;
    if (t < 26) {
        float v;
        if (t < 24)      v = P1[((size_t)(b*24 + t))*25 + cell] * SS4[t] + SS4[24 + t];
        else if (t == 24) v = ((float)cell / 5.f - 2.f) * 0.5f;
        else              v = ((float)(cell % 5) - 2.f) * 0.5f;
        f[t] = v;
    }
    __syncthreads();
    float su = 0.f, sv = 0.f;
    #pragma unroll
    for (int k = 0; k < 26; ++k) {
        su += f[k] * w1uvT[k*256 + t];
        sv += f[k] * w1uvT[(26 + k)*256 + t];
    }
    Ub[(size_t)row*256 + t] = su;
    Vb[(size_t)row*256 + t] = sv;
}

// ---------------- Q — EXACT round-5/8 ----------------
__global__ __launch_bounds__(256) void k_q(
    const float* __restrict__ P1, const float* __restrict__ SS4,
    const float* __restrict__ w1qT, const float* __restrict__ gb, float* __restrict__ Qb)
{
    __shared__ float f[650];
    const int b = blockIdx.x, t = threadIdx.x;
    for (int i = t; i < 650; i += 256) {
        const int cell = i / 26, ff = i % 26;
        float v;
        if (ff < 24)      v = P1[((size_t)((64 + b)*24 + ff))*25 + cell] * SS4[48 + ff] + SS4[72 + ff];
        else if (ff == 24) v = ((float)cell / 5.f - 2.f) * 0.5f;
        else               v = ((float)(cell % 5) - 2.f) * 0.5f;
        f[i] = v;
    }
    __syncthreads();
    float s = gb[t];
    #pragma unroll 2
    for (int k = 0; k < 650; ++k) s += f[k] * w1qT[k*256 + t];
    Qb[b*256 + t] = s;
}

// ---------------- MFMA g-MLP (bf16x3) + sum pool — EXACT round-5/8 ----------------
__global__ __launch_bounds__(256) void k_gmlp(
    const float* __restrict__ U, const float* __restrict__ V, const float* __restrict__ Q,
    const unsigned short* __restrict__ WP, const float* __restrict__ gb, float* __restrict__ xg)
{
    __shared__ unsigned short hhi[16384];   // 64x256 bf16 = 32 KB
    __shared__ unsigned short hlo[16384];
    const int b    = blockIdx.x / 10;
    const int row0 = (blockIdx.x % 10) * 64;
    const int tid  = threadIdx.x;
    const int lane = tid & 63, w = tid >> 6;
    const int r0 = w * 16;

    {
        const float2* Q2 = (const float2*)(Q + b*256);
        const float2 q0 = Q2[lane], q1 = Q2[64 + lane];
        for (int rr = 0; rr < 16; ++rr) {
            const int row = r0 + rr;
            int p = row0 + row; if (p > 624) p = 624;
            const float2* u2p = (const float2*)(U + ((size_t)(b*25 + p % 25)) * 256);
            const float2* v2p = (const float2*)(V + ((size_t)(b*25 + p / 25)) * 256);
            #pragma unroll
            for (int cc = 0; cc < 2; ++cc) {
                const int cp = cc*64 + lane;
                const float2 u2 = u2p[cp], v2 = v2p[cp];
                const float2 q2 = cc ? q1 : q0;
                const float x0 = fmaxf(u2.x + v2.x + q2.x, 0.f);
                const float x1 = fmaxf(u2.y + v2.y + q2.y, 0.f);
                const unsigned short h0 = f2bf(x0), h1 = f2bf(x1);
                const float l0 = x0 - bf2f(h0), l1 = x1 - bf2f(h1);
                const int byte = (row*512 + cp*4) ^ ((row & 7) << 4);
                *(unsigned*)((char*)hhi + byte) = (unsigned)h0 | ((unsigned)h1 << 16);
                *(unsigned*)((char*)hlo + byte) = (unsigned)f2bf(l0) | ((unsigned)f2bf(l1) << 16);
            }
        }
    }
    __syncthreads();

    f32x4 acc[16];
    #pragma unroll 1
    for (int l = 0; l < 3; ++l) {
        #pragma unroll
        for (int nt = 0; nt < 16; ++nt) acc[nt] = (f32x4)0.f;
        const int ar = r0 + (lane & 15);
        #pragma unroll 1
        for (int kb = 0; kb < 8; ++kb) {
            const int off = (ar*512 + kb*64 + (lane >> 4)*16) ^ ((ar & 7) << 4);
            const bf16x8 ahi = *(const bf16x8*)((char*)hhi + off);
            const bf16x8 alo = *(const bf16x8*)((char*)hlo + off);
            const bf16x8* whi = (const bf16x8*)WP + ((size_t)(l*8 + kb)*16)*64 + lane;
            const bf16x8* wlo = whi + 24576;
            #pragma unroll
            for (int nt = 0; nt < 16; ++nt) {
                const bf16x8 bh = whi[nt*64];
                const bf16x8 bl = wlo[nt*64];
                acc[nt] = __builtin_amdgcn_mfma_f32_16x16x32_bf16(ahi, bh, acc[nt], 0, 0, 0);
                acc[nt] = __builtin_amdgcn_mfma_f32_16x16x32_bf16(ahi, bl, acc[nt], 0, 0, 0);
                acc[nt] = __builtin_amdgcn_mfma_f32_16x16x32_bf16(alo, bh, acc[nt], 0, 0, 0);
            }
        }
        __syncthreads();
        if (l < 2) {
            #pragma unroll
            for (int nt = 0; nt < 16; ++nt) {
                const int col = nt*16 + (lane & 15);
                const float bias = gb[(l+1)*256 + col];
                #pragma unroll
                for (int r = 0; r < 4; ++r) {
                    const int row = r0 + 4*(lane >> 4) + r;
                    const float v = fmaxf(acc[nt][r] + bias, 0.f);
                    const unsigned short hv = f2bf(v);
                    const float lv = v - bf2f(hv);
                    const int byte = (row*512 + col*2) ^ ((row & 7) << 4);
                    *(unsigned short*)((char*)hhi + byte) = hv;
                    *(unsigned short*)((char*)hlo + byte) = f2bf(lv);
                }
            }
            __syncthreads();
        } else {
            #pragma unroll
            for (int nt = 0; nt < 16; ++nt) {
                const int col = nt*16 + (lane & 15);
                const float bias = gb[3*256 + col];
                float s = 0.f;
                #pragma unroll
                for (int r = 0; r < 4; ++r) {
                    const int row = r0 + 4*(lane >> 4) + r;
                    if (row0 + row < 625) s += fmaxf(acc[nt][r] + bias, 0.f);
                }
                s += __shfl_xor(s, 16);
                s += __shfl_xor(s, 32);
                if (lane < 16) atomicAdd(&xg[b*256 + col], s);
            }
        }
    }
}

// ---------------- fused head — EXACT round-5/8 ----------------
__global__ __launch_bounds__(256) void k_head(
    const float* __restrict__ XG, const float* __restrict__ fw1T, const float* __restrict__ fb1,
    const float* __restrict__ fc2T, const float* __restrict__ fc2b,
    const float* __restrict__ fc3T, const float* __restrict__ fc3b, float* __restrict__ out)
{
    __shared__ float xa[256], xb[256], ys[128];
    const int b = blockIdx.x, t = threadIdx.x;
    xa[t] = XG[b*256 + t];
    __syncthreads();
    float s = fb1[t];
    #pragma unroll 4
    for (int k = 0; k < 256; ++k) s += xa[k] * fw1T[k*256 + t];
    xb[t] = fmaxf(s, 0.f);
    __syncthreads();
    s = fc2b[t];
    #pragma unroll 4
    for (int k = 0; k < 256; ++k) s += xb[k] * fc2T[k*256 + t];
    xa[t] = fmaxf(s, 0.f);
    __syncthreads();
    if (t < 128) {
        s = fc3b[t];
        #pragma unroll 4
        for (int k = 0; k < 256; ++k) s += xa[k] * fc3T[k*128 + t];
        ys[t] = s;
    }
    __syncthreads();
    if (t < 16) {
        float m = ys[t*8];
        #pragma unroll
        for (int i = 1; i < 8; ++i) m = fmaxf(m, ys[t*8 + i]);
        float e[8], sum = 0.f;
        #pragma unroll
        for (int i = 0; i < 8; ++i) { e[i] = expf(ys[t*8 + i] - m); sum += e[i]; }
        const float inv = 1.f / sum;
        #pragma unroll
        for (int i = 0; i < 8; ++i) out[b*128 + t*8 + i] = fmaxf(e[i]*inv, 0.001f);
    }
}

extern "C" void kernel_launch(void* const* d_in, const int* in_sizes, int n_in,
                              void* d_out, int out_size, void* d_ws, size_t ws_size,
                              hipStream_t stream)
{
    const float* img   = (const float*)d_in[0];
    const float* img2  = (const float*)d_in[1];
    const float* cw1   = (const float*)d_in[2];
    const float* cw234 = (const float*)d_in[3];
    const float* cb    = (const float*)d_in[4];
    const float* bng   = (const float*)d_in[5];
    const float* bnb   = (const float*)d_in[6];
    const float* gw1   = (const float*)d_in[7];
    const float* gw234 = (const float*)d_in[8];
    const float* gb    = (const float*)d_in[9];
    const float* fw1   = (const float*)d_in[10];
    const float* fb1   = (const float*)d_in[11];
    const float* fc2w  = (const float*)d_in[12];
    const float* fc2b  = (const float*)d_in[13];
    const float* fc3w  = (const float*)d_in[14];
    const float* fc3b  = (const float*)d_in[15];

    float* ws = (float*)d_ws;
    float* P0 = ws + OFF_P0;  float* P1 = ws + OFF_P1;   float* SS  = ws + OFF_SS;
    float* SA = ws + OFF_SACC; float* Ub = ws + OFF_U;   float* Vb  = ws + OFF_V;
    float* Qb = ws + OFF_Q;
    unsigned short* WP = (unsigned short*)(ws + OFF_WP);
    float* W1UV = ws + OFF_W1UV; float* W1Q = ws + OFF_W1Q;
    float* FW1T = ws + OFF_FW1T; float* FC2T = ws + OFF_FC2T; float* FC3T = ws + OFF_FC3T;
    float* XG = ws + OFF_XG;
    float* out = (float*)d_out;

    hipLaunchKernelGGL(k_prep, dim3(1599), dim3(256), 0, stream, gw1, gw234, fw1, fc2w, fc3w, ws);

    hipLaunchKernelGGL(k_conv_first, dim3(19200), dim3(256), 0, stream, img, img2, cw1, cb, P0);
    hipLaunchKernelGGL(k_stats_part, dim3(384), dim3(256), 0, stream, P0, SA, 1600);
    hipLaunchKernelGGL(k_stats_fin,  dim3(1),   dim3(64),  0, stream, SA, bng, bnb, SS, 1600);
    // conv2: 40x40 -> 20x20; TH=4, nty=5
    hipLaunchKernelGGL(k_convL, dim3(640), dim3(256), 0, stream,
                       P0, SS, cw234, cb + 24, P1, 40, 40, 20, 20, 4, 5);
    hipLaunchKernelGGL(k_stats, dim3(48), dim3(256), 0, stream, P1, bng+24, bnb+24, SS+96, 400);
    // conv3: 20x20 -> 10x10; TH=5, nty=2
    hipLaunchKernelGGL(k_convL, dim3(256), dim3(256), 0, stream,
                       P1, SS + 96, cw234 + 5184, cb + 48, P0, 20, 20, 10, 10, 5, 2);
    hipLaunchKernelGGL(k_stats, dim3(48), dim3(256), 0, stream, P0, bng+48, bnb+48, SS+192, 100);
    // conv4: 10x10 -> 5x5; TH=5, nty=1
    hipLaunchKernelGGL(k_convL, dim3(128), dim3(256), 0, stream,
                       P0, SS + 192, cw234 + 10368, cb + 72, P1, 10, 10, 5, 5, 5, 1);
    hipLaunchKernelGGL(k_stats, dim3(48), dim3(256), 0, stream, P1, bng+72, bnb+72, SS+288, 25);

    hipLaunchKernelGGL(k_uv, dim3(1600), dim3(256), 0, stream, P1, SS+288, W1UV, Ub, Vb);
    hipLaunchKernelGGL(k_q,  dim3(64),   dim3(256), 0, stream, P1, SS+288, W1Q, gb, Qb);

    hipLaunchKernelGGL(k_gmlp, dim3(640), dim3(256), 0, stream, Ub, Vb, Qb, WP, gb, XG);

    hipLaunchKernelGGL(k_head, dim3(64), dim3(256), 0, stream,
                       XG, FW1T, fb1, FC2T, fc2b, FC3T, fc3b, out);
}

// Round 10
// 511.260 us; speedup vs baseline: 1.7111x; 1.1741x over previous
//
#include <hip/hip_runtime.h>

typedef short bf16x8 __attribute__((ext_vector_type(8)));
typedef float f32x4  __attribute__((ext_vector_type(4)));

#define EPSF 1e-5f

// ---------------- workspace layout (float element offsets) — EXACT round-5/8/9 ----------------
#define OFF_P0   0          // 4,915,200 (conv ping)
#define OFF_U    1048576    //   409,600 (in P0 tail; conv3 out = 307,200 -> no overlap)
#define OFF_V    1572864    //   409,600
#define OFF_P1   4915200    // 1,228,800 (conv pong)
#define OFF_SS   6144000    // 384
#define OFF_SACC 6144384    // 96 (+pad)
#define OFF_Q    6144512    // 16,384
#define OFF_WP   6160896    // 196,608 float-slots: WP_hi + WP_lo bf16 frags
#define OFF_W1UV 6357504    // 13,312  (52 x 256)
#define OFF_W1Q  6370816    // 166,400 (650 x 256)
#define OFF_FW1T 6537216    // 65,536
#define OFF_FC2T 6602752    // 65,536
#define OFF_FC3T 6668288    // 32,768
#define OFF_XG   6701056    // 16,384
// end: 6,717,440 floats = 25.6 MiB

__device__ __forceinline__ unsigned short f2bf(float f) {
    union { float f; unsigned u; } cv; cv.f = f;
    const unsigned u = cv.u;
    return (unsigned short)((u + 0x7fffu + ((u >> 16) & 1u)) >> 16);  // RNE
}
__device__ __forceinline__ float bf2f(unsigned short h) {
    union { unsigned u; float f; } cv; cv.u = (unsigned)h << 16; return cv.f;
}

// ---------------- prep — EXACT round-5/8/9 ----------------
__global__ __launch_bounds__(256) void k_prep(
    const float* __restrict__ gw1, const float* __restrict__ gw234,
    const float* __restrict__ fw1, const float* __restrict__ fc2w,
    const float* __restrict__ fc3w, float* __restrict__ ws)
{
    int idx = blockIdx.x * 256 + threadIdx.x;
    if (idx < 16384) { ws[OFF_XG + idx] = 0.f; return; }
    idx -= 16384;
    if (idx < 96) { ws[OFF_SACC + idx] = 0.f; return; }
    idx -= 96;
    if (idx < 49152) {
        const int isLo = idx >= 24576;
        const int f = isLo ? idx - 24576 : idx;
        const int lane = f & 63;
        const int nt = (f >> 6) & 15;
        const int kb = (f >> 10) & 7;
        const int l  = f >> 13;
        const int o = nt * 16 + (lane & 15);
        const int k = kb * 32 + (lane >> 4) * 8;
        const float* src = gw234 + ((size_t)l * 256 + o) * 256 + k;
        unsigned short* dst = (unsigned short*)(ws + OFF_WP) + (size_t)idx * 8;
        #pragma unroll
        for (int j = 0; j < 8; ++j) {
            const float x = src[j];
            const unsigned short hi = f2bf(x);
            dst[j] = isLo ? f2bf(x - bf2f(hi)) : hi;
        }
        return;
    }
    idx -= 49152;
    if (idx < 13312) {
        const int o = idx & 255, k = idx >> 8;
        ws[OFF_W1UV + idx] = gw1[(size_t)o * 702 + k];
        return;
    }
    idx -= 13312;
    if (idx < 166400) {
        const int o = idx & 255, k = idx >> 8;
        ws[OFF_W1Q + idx] = gw1[(size_t)o * 702 + 52 + k];
        return;
    }
    idx -= 166400;
    if (idx < 65536) { const int o = idx & 255, k = idx >> 8; ws[OFF_FW1T + idx] = fw1[o * 256 + k];  return; }
    idx -= 65536;
    if (idx < 65536) { const int o = idx & 255, k = idx >> 8; ws[OFF_FC2T + idx] = fc2w[o * 256 + k]; return; }
    idx -= 65536;
    if (idx < 32768) { const int o = idx & 127, k = idx >> 7; ws[OFF_FC3T + idx] = fc3w[o * 256 + k]; return; }
}

// ---------------- conv layer 1 — EXACT round-8/9 ----------------
__global__ __launch_bounds__(256) void k_conv_first(
    const float* __restrict__ img, const float* __restrict__ img2,
    const float* __restrict__ w, const float* __restrict__ bias,
    float* __restrict__ out)
{
    const int idx = blockIdx.x * 256 + threadIdx.x;
    if (idx >= 128*24*40*40) return;
    const int wo = idx % 40;
    const int ho = (idx / 40) % 40;
    const int co = (idx / 1600) % 24;
    const int b  = idx / (1600*24);
    const float* in = (b < 64 ? img : img2) + (size_t)(b & 63) * 3 * 6400;
    float s = bias[co];
    if (ho >= 1 && wo >= 1) {
        const float* p0 = in + (2*ho - 1)*80 + (2*wo - 1);
        #pragma unroll
        for (int ci = 0; ci < 3; ++ci) {
            const float* p  = p0 + (size_t)ci * 6400;
            const float* wp = w + (co*3 + ci) * 9;
            s += p[0]  *wp[0] + p[1]  *wp[1] + p[2]  *wp[2]
               + p[80] *wp[3] + p[81] *wp[4] + p[82] *wp[5]
               + p[160]*wp[6] + p[161]*wp[7] + p[162]*wp[8];
        }
    } else {
        for (int ci = 0; ci < 3; ++ci) {
            const float* ip = in + (size_t)ci * 6400;
            const float* wp = w + (co*3 + ci) * 9;
            #pragma unroll
            for (int kh = 0; kh < 3; ++kh) {
                const int ih = 2*ho - 1 + kh;
                if (ih < 0 || ih >= 80) continue;
                #pragma unroll
                for (int kw = 0; kw < 3; ++kw) {
                    const int iw = 2*wo - 1 + kw;
                    if (iw < 0 || iw >= 80) continue;
                    s += ip[ih*80 + iw] * wp[kh*3 + kw];
                }
            }
        }
    }
    out[idx] = fmaxf(s, 0.f);
}

// ---------------- LDS-tiled conv, layers 2-4 — EXACT round-9 ----------------
__global__ __launch_bounds__(256) void k_convL(
    const float* __restrict__ in, const float* __restrict__ ss,
    const float* __restrict__ w, const float* __restrict__ bias,
    float* __restrict__ out, int IH, int IW, int OH, int OW, int TH, int nty)
{
    __shared__ float lds[14280];
    const int NR = 2*TH + 1, CSTR = IW + 2;
    float* lin   = lds;
    float* lw    = lds + 24 * NR * CSTR;
    float* lbias = lw + 5184;

    const int b  = blockIdx.x / nty;
    const int ty = blockIdx.x % nty;
    const int oy0 = ty * TH;
    const int t = threadIdx.x;

    for (int i = t; i < 5184; i += 256) {
        const int co = i % 24, tap = (i / 24) % 9, ci = i / 216;
        lw[i] = w[(co*24 + ci)*9 + tap];
    }
    if (t < 24) lbias[t] = bias[t];

    const float* sc = ss + (b >> 6) * 48;
    for (int i = t; i < 24 * NR * CSTR; i += 256) {
        const int ci = i / (NR * CSTR);
        const int r  = i % (NR * CSTR);
        const int y  = r / CSTR, x = r % CSTR;
        const int gy = 2*oy0 - 1 + y, gx = x - 1;
        float v = 0.f;
        if (gy >= 0 && gy < IH && gx >= 0 && gx < IW)
            v = in[(((size_t)b*24 + ci)*IH + gy)*IW + gx] * sc[ci] + sc[24 + ci];
        lin[i] = v;
    }
    __syncthreads();

    const int THe = min(TH, OH - oy0);
    const int PPR = (OW + 1) >> 1;
    const int NWI = THe * PPR * 24;
    for (int wk = t; wk < NWI; wk += 256) {
        const int co = wk % 24;
        const int pr = wk / 24;
        const int i2 = (pr % PPR) * 2;
        const int j  = pr / PPR;
        const bool hasB = (i2 + 1 < OW);
        float sA = lbias[co], sB = sA;
        const float* wp = lw + co;
        for (int ci = 0; ci < 24; ++ci) {
            const int base = (ci*NR + 2*j)*CSTR + 2*i2;
            const float* wc = wp + ci * 216;
            #pragma unroll
            for (int kh = 0; kh < 3; ++kh) {
                const float* lr = lin + base + kh*CSTR;
                const float2 fa = *(const float2*)lr;
                const float2 fb = *(const float2*)(lr + 2);
                const float  fc = hasB ? lr[4] : 0.f;
                const float w0 = wc[(kh*3 + 0)*24];
                const float w1 = wc[(kh*3 + 1)*24];
                const float w2 = wc[(kh*3 + 2)*24];
                sA += fa.x*w0 + fa.y*w1 + fb.x*w2;
                sB += fb.x*w0 + fb.y*w1 + fc  *w2;
            }
        }
        const size_t o = (((size_t)b*24 + co)*OH + oy0 + j)*OW + i2;
        out[o] = fmaxf(sA, 0.f);
        if (hasB) out[o + 1] = fmaxf(sB, 0.f);
    }
}

// ---------------- split-k BN stats (layer 1) — EXACT round-5/8/9 ----------------
__global__ __launch_bounds__(256) void k_stats_part(
    const float* __restrict__ y, float* __restrict__ sacc, int HW)
{
    const int img = blockIdx.x / (24*8);
    const int c   = (blockIdx.x / 8) % 24;
    const int sp  = blockIdx.x % 8;
    const int N = 64 * HW, chunk = N / 8;
    float sum = 0.f, sq = 0.f;
    for (int i = sp*chunk + threadIdx.x; i < (sp+1)*chunk; i += 256) {
        const int bb = i / HW, j = i - bb*HW;
        const float v = y[(size_t)((img*64 + bb)*24 + c) * HW + j];
        sum += v; sq += v*v;
    }
    #pragma unroll
    for (int off = 32; off > 0; off >>= 1) {
        sum += __shfl_down(sum, off);
        sq  += __shfl_down(sq, off);
    }
    __shared__ float red[8];
    const int lane = threadIdx.x & 63, wid = threadIdx.x >> 6;
    if (lane == 0) { red[wid] = sum; red[4 + wid] = sq; }
    __syncthreads();
    if (threadIdx.x == 0) {
        atomicAdd(&sacc[img*24 + c],      red[0]+red[1]+red[2]+red[3]);
        atomicAdd(&sacc[48 + img*24 + c], red[4]+red[5]+red[6]+red[7]);
    }
}

__global__ void k_stats_fin(const float* __restrict__ sacc, const float* __restrict__ g,
                            const float* __restrict__ beta, float* __restrict__ ss, int HW)
{
    const int t = threadIdx.x;
    if (t >= 48) return;
    const int img = t / 24, c = t % 24;
    const float N = 64.f * (float)HW;
    const float mean = sacc[t] / N;
    const float var  = sacc[48 + t] / N - mean*mean;
    const float scale = g[c] * rsqrtf(var + EPSF);
    ss[img*48 + c]      = scale;
    ss[img*48 + 24 + c] = beta[c] - mean * scale;
}

// ---------------- single-pass BN stats (layers 2-4) — EXACT round-5/8/9 ----------------
__global__ __launch_bounds__(256) void k_stats(
    const float* __restrict__ y, const float* __restrict__ g, const float* __restrict__ beta,
    float* __restrict__ ss, int HW)
{
    const int img = blockIdx.x / 24, c = blockIdx.x % 24;
    const int N = 64 * HW;
    float sum = 0.f, sq = 0.f;
    for (int i = threadIdx.x; i < N; i += 256) {
        const int bb = i / HW, j = i - bb*HW;
        const float v = y[(size_t)((img*64 + bb)*24 + c) * HW + j];
        sum += v; sq += v*v;
    }
    #pragma unroll
    for (int off = 32; off > 0; off >>= 1) {
        sum += __shfl_down(sum, off);
        sq  += __shfl_down(sq, off);
    }
    __shared__ float red[8];
    const int lane = threadIdx.x & 63, wid = threadIdx.x >> 6;
    if (lane == 0) { red[wid] = sum; red[4 + wid] = sq; }
    __syncthreads();
    if (threadIdx.x == 0) {
        const float S  = red[0]+red[1]+red[2]+red[3];
        const float Q2 = red[4]+red[5]+red[6]+red[7];
        const float mean = S / (float)N;
        const float var  = Q2 / (float)N - mean*mean;
        const float scale = g[c] * rsqrtf(var + EPSF);
        ss[img*48 + c]      = scale;
        ss[img*48 + 24 + c] = beta[c] - mean * scale;
    }
}

// ---------------- U,V — EXACT round-5/8/9 ----------------
__global__ __launch_bounds__(256) void k_uv(
    const float* __restrict__ P1, const float* __restrict__ SS4,
    const float* __restrict__ w1uvT, float* __restrict__ Ub, float* __restrict__ Vb)
{
    __shared__ float f[26];
    const int row = blockIdx.x;           // b*25+cell, b<64 (img1)
    const int b = row / 25, cell = row % 25;
    const int t = threadIdx.x;
    if (t < 26) {
        float v;
        if (t < 24)      v = P1[((size_t)(b*24 + t))*25 + cell] * SS4[t] + SS4[24 + t];
        else if (t == 24) v = ((float)cell / 5.f - 2.f) * 0.5f;
        else              v = ((float)(cell % 5) - 2.f) * 0.5f;
        f[t] = v;
    }
    __syncthreads();
    float su = 0.f, sv = 0.f;
    #pragma unroll
    for (int k = 0; k < 26; ++k) {
        su += f[k] * w1uvT[k*256 + t];
        sv += f[k] * w1uvT[(26 + k)*256 + t];
    }
    Ub[(size_t)row*256 + t] = su;
    Vb[(size_t)row*256 + t] = sv;
}

// ---------------- Q — EXACT round-5/8/9 ----------------
__global__ __launch_bounds__(256) void k_q(
    const float* __restrict__ P1, const float* __restrict__ SS4,
    const float* __restrict__ w1qT, const float* __restrict__ gb, float* __restrict__ Qb)
{
    __shared__ float f[650];
    const int b = blockIdx.x, t = threadIdx.x;
    for (int i = t; i < 650; i += 256) {
        const int cell = i / 26, ff = i % 26;
        float v;
        if (ff < 24)      v = P1[((size_t)((64 + b)*24 + ff))*25 + cell] * SS4[48 + ff] + SS4[72 + ff];
        else if (ff == 24) v = ((float)cell / 5.f - 2.f) * 0.5f;
        else               v = ((float)(cell % 5) - 2.f) * 0.5f;
        f[i] = v;
    }
    __syncthreads();
    float s = gb[t];
    #pragma unroll 2
    for (int k = 0; k < 650; ++k) s += f[k] * w1qT[k*256 + t];
    Qb[b*256 + t] = s;
}

// ---------------- MFMA g-MLP (bf16x3) + sum pool — column-stripe wave ownership ----------------
// Round-10 change: wave w computes ALL 64 rows x its 4 nt column-tiles (nt = w*4..w*4+3)
// instead of 16 rows x all 16 nt. Each B-fragment now feeds 4 MFMAs (4 rowsets) ->
// per-wave weight traffic drops 4x (the round-9 limiter: 2 GB of L1/L2 weight streaming,
// MfmaUtil 10%). acc stays 16 x f32x4 (4 rowsets x 4 nt); accumulation order per output
// unchanged -> bitwise-identical results. NOTE rule #20: all acc/frag indices compile-time.
__global__ __launch_bounds__(256) void k_gmlp(
    const float* __restrict__ U, const float* __restrict__ V, const float* __restrict__ Q,
    const unsigned short* __restrict__ WP, const float* __restrict__ gb, float* __restrict__ xg)
{
    __shared__ unsigned short hhi[16384];   // 64x256 bf16 = 32 KB
    __shared__ unsigned short hlo[16384];
    const int b    = blockIdx.x / 10;
    const int row0 = (blockIdx.x % 10) * 64;
    const int tid  = threadIdx.x;
    const int lane = tid & 63, w = tid >> 6;

    // layer 1 fill: wave fills rows [w*16, w*16+16) — unchanged (barrier below)
    {
        const int r0 = w * 16;
        const float2* Q2 = (const float2*)(Q + b*256);
        const float2 q0 = Q2[lane], q1 = Q2[64 + lane];
        for (int rr = 0; rr < 16; ++rr) {
            const int row = r0 + rr;
            int p = row0 + row; if (p > 624) p = 624;
            const float2* u2p = (const float2*)(U + ((size_t)(b*25 + p % 25)) * 256);
            const float2* v2p = (const float2*)(V + ((size_t)(b*25 + p / 25)) * 256);
            #pragma unroll
            for (int cc = 0; cc < 2; ++cc) {
                const int cp = cc*64 + lane;
                const float2 u2 = u2p[cp], v2 = v2p[cp];
                const float2 q2 = cc ? q1 : q0;
                const float x0 = fmaxf(u2.x + v2.x + q2.x, 0.f);
                const float x1 = fmaxf(u2.y + v2.y + q2.y, 0.f);
                const unsigned short h0 = f2bf(x0), h1 = f2bf(x1);
                const float l0 = x0 - bf2f(h0), l1 = x1 - bf2f(h1);
                const int byte = (row*512 + cp*4) ^ ((row & 7) << 4);
                *(unsigned*)((char*)hhi + byte) = (unsigned)h0 | ((unsigned)h1 << 16);
                *(unsigned*)((char*)hlo + byte) = (unsigned)f2bf(l0) | ((unsigned)f2bf(l1) << 16);
            }
        }
    }
    __syncthreads();

    f32x4 acc[4][4];   // [rowset][n]
    #pragma unroll 1
    for (int l = 0; l < 3; ++l) {
        #pragma unroll
        for (int rs = 0; rs < 4; ++rs)
            #pragma unroll
            for (int n = 0; n < 4; ++n) acc[rs][n] = (f32x4)0.f;

        #pragma unroll 1
        for (int kb = 0; kb < 8; ++kb) {
            bf16x8 ahi[4], alo[4];
            #pragma unroll
            for (int rs = 0; rs < 4; ++rs) {
                const int ar = rs*16 + (lane & 15);
                const int off = (ar*512 + kb*64 + (lane >> 4)*16) ^ ((ar & 7) << 4);
                ahi[rs] = *(const bf16x8*)((char*)hhi + off);
                alo[rs] = *(const bf16x8*)((char*)hlo + off);
            }
            #pragma unroll
            for (int n = 0; n < 4; ++n) {
                const int nt = w*4 + n;
                const bf16x8* whi = (const bf16x8*)WP + ((size_t)((l*8 + kb)*16 + nt))*64 + lane;
                const bf16x8 bh = whi[0];
                const bf16x8 bl = whi[24576];   // lo copy: +24576 fragments
                #pragma unroll
                for (int rs = 0; rs < 4; ++rs) {
                    acc[rs][n] = __builtin_amdgcn_mfma_f32_16x16x32_bf16(ahi[rs], bh, acc[rs][n], 0, 0, 0);
                    acc[rs][n] = __builtin_amdgcn_mfma_f32_16x16x32_bf16(ahi[rs], bl, acc[rs][n], 0, 0, 0);
                    acc[rs][n] = __builtin_amdgcn_mfma_f32_16x16x32_bf16(alo[rs], bh, acc[rs][n], 0, 0, 0);
                }
            }
        }
        __syncthreads();   // all reads of h done before overwrite
        if (l < 2) {
            #pragma unroll
            for (int n = 0; n < 4; ++n) {
                const int col = (w*4 + n)*16 + (lane & 15);
                const float bias = gb[(l+1)*256 + col];
                #pragma unroll
                for (int rs = 0; rs < 4; ++rs) {
                    #pragma unroll
                    for (int r = 0; r < 4; ++r) {
                        const int row = rs*16 + 4*(lane >> 4) + r;
                        const float v = fmaxf(acc[rs][n][r] + bias, 0.f);
                        const unsigned short hv = f2bf(v);
                        const float lv = v - bf2f(hv);
                        const int byte = (row*512 + col*2) ^ ((row & 7) << 4);
                        *(unsigned short*)((char*)hhi + byte) = hv;
                        *(unsigned short*)((char*)hlo + byte) = f2bf(lv);
                    }
                }
            }
            __syncthreads();
        } else {
            #pragma unroll
            for (int n = 0; n < 4; ++n) {
                const int col = (w*4 + n)*16 + (lane & 15);
                const float bias = gb[3*256 + col];
                float s = 0.f;
                #pragma unroll
                for (int rs = 0; rs < 4; ++rs) {
                    #pragma unroll
                    for (int r = 0; r < 4; ++r) {
                        const int row = rs*16 + 4*(lane >> 4) + r;
                        if (row0 + row < 625) s += fmaxf(acc[rs][n][r] + bias, 0.f);
                    }
                }
                s += __shfl_xor(s, 16);
                s += __shfl_xor(s, 32);
                if (lane < 16) atomicAdd(&xg[b*256 + col], s);
            }
        }
    }
}

// ---------------- fused head — EXACT round-5/8/9 ----------------
__global__ __launch_bounds__(256) void k_head(
    const float* __restrict__ XG, const float* __restrict__ fw1T, const float* __restrict__ fb1,
    const float* __restrict__ fc2T, const float* __restrict__ fc2b,
    const float* __restrict__ fc3T, const float* __restrict__ fc3b, float* __restrict__ out)
{
    __shared__ float xa[256], xb[256], ys[128];
    const int b = blockIdx.x, t = threadIdx.x;
    xa[t] = XG[b*256 + t];
    __syncthreads();
    float s = fb1[t];
    #pragma unroll 4
    for (int k = 0; k < 256; ++k) s += xa[k] * fw1T[k*256 + t];
    xb[t] = fmaxf(s, 0.f);
    __syncthreads();
    s = fc2b[t];
    #pragma unroll 4
    for (int k = 0; k < 256; ++k) s += xb[k] * fc2T[k*256 + t];
    xa[t] = fmaxf(s, 0.f);
    __syncthreads();
    if (t < 128) {
        s = fc3b[t];
        #pragma unroll 4
        for (int k = 0; k < 256; ++k) s += xa[k] * fc3T[k*128 + t];
        ys[t] = s;
    }
    __syncthreads();
    if (t < 16) {
        float m = ys[t*8];
        #pragma unroll
        for (int i = 1; i < 8; ++i) m = fmaxf(m, ys[t*8 + i]);
        float e[8], sum = 0.f;
        #pragma unroll
        for (int i = 0; i < 8; ++i) { e[i] = expf(ys[t*8 + i] - m); sum += e[i]; }
        const float inv = 1.f / sum;
        #pragma unroll
        for (int i = 0; i < 8; ++i) out[b*128 + t*8 + i] = fmaxf(e[i]*inv, 0.001f);
    }
}

extern "C" void kernel_launch(void* const* d_in, const int* in_sizes, int n_in,
                              void* d_out, int out_size, void* d_ws, size_t ws_size,
                              hipStream_t stream)
{
    const float* img   = (const float*)d_in[0];
    const float* img2  = (const float*)d_in[1];
    const float* cw1   = (const float*)d_in[2];
    const float* cw234 = (const float*)d_in[3];
    const float* cb    = (const float*)d_in[4];
    const float* bng   = (const float*)d_in[5];
    const float* bnb   = (const float*)d_in[6];
    const float* gw1   = (const float*)d_in[7];
    const float* gw234 = (const float*)d_in[8];
    const float* gb    = (const float*)d_in[9];
    const float* fw1   = (const float*)d_in[10];
    const float* fb1   = (const float*)d_in[11];
    const float* fc2w  = (const float*)d_in[12];
    const float* fc2b  = (const float*)d_in[13];
    const float* fc3w  = (const float*)d_in[14];
    const float* fc3b  = (const float*)d_in[15];

    float* ws = (float*)d_ws;
    float* P0 = ws + OFF_P0;  float* P1 = ws + OFF_P1;   float* SS  = ws + OFF_SS;
    float* SA = ws + OFF_SACC; float* Ub = ws + OFF_U;   float* Vb  = ws + OFF_V;
    float* Qb = ws + OFF_Q;
    unsigned short* WP = (unsigned short*)(ws + OFF_WP);
    float* W1UV = ws + OFF_W1UV; float* W1Q = ws + OFF_W1Q;
    float* FW1T = ws + OFF_FW1T; float* FC2T = ws + OFF_FC2T; float* FC3T = ws + OFF_FC3T;
    float* XG = ws + OFF_XG;
    float* out = (float*)d_out;

    hipLaunchKernelGGL(k_prep, dim3(1599), dim3(256), 0, stream, gw1, gw234, fw1, fc2w, fc3w, ws);

    hipLaunchKernelGGL(k_conv_first, dim3(19200), dim3(256), 0, stream, img, img2, cw1, cb, P0);
    hipLaunchKernelGGL(k_stats_part, dim3(384), dim3(256), 0, stream, P0, SA, 1600);
    hipLaunchKernelGGL(k_stats_fin,  dim3(1),   dim3(64),  0, stream, SA, bng, bnb, SS, 1600);
    // conv2: 40x40 -> 20x20; TH=4, nty=5
    hipLaunchKernelGGL(k_convL, dim3(640), dim3(256), 0, stream,
                       P0, SS, cw234, cb + 24, P1, 40, 40, 20, 20, 4, 5);
    hipLaunchKernelGGL(k_stats, dim3(48), dim3(256), 0, stream, P1, bng+24, bnb+24, SS+96, 400);
    // conv3: 20x20 -> 10x10; TH=5, nty=2
    hipLaunchKernelGGL(k_convL, dim3(256), dim3(256), 0, stream,
                       P1, SS + 96, cw234 + 5184, cb + 48, P0, 20, 20, 10, 10, 5, 2);
    hipLaunchKernelGGL(k_stats, dim3(48), dim3(256), 0, stream, P0, bng+48, bnb+48, SS+192, 100);
    // conv4: 10x10 -> 5x5; TH=5, nty=1
    hipLaunchKernelGGL(k_convL, dim3(128), dim3(256), 0, stream,
                       P0, SS + 192, cw234 + 10368, cb + 72, P1, 10, 10, 5, 5, 5, 1);
    hipLaunchKernelGGL(k_stats, dim3(48), dim3(256), 0, stream, P1, bng+72, bnb+72, SS+288, 25);

    hipLaunchKernelGGL(k_uv, dim3(1600), dim3(256), 0, stream, P1, SS+288, W1UV, Ub, Vb);
    hipLaunchKernelGGL(k_q,  dim3(64),   dim3(256), 0, stream, P1, SS+288, W1Q, gb, Qb);

    hipLaunchKernelGGL(k_gmlp, dim3(640), dim3(256), 0, stream, Ub, Vb, Qb, WP, gb, XG);

    hipLaunchKernelGGL(k_head, dim3(64), dim3(256), 0, stream,
                       XG, FW1T, fb1, FC2T, fc2b, FC3T, fc3b, out);
}

// Round 11
// 360.440 us; speedup vs baseline: 2.4271x; 1.4184x over previous
//
#include <hip/hip_runtime.h>

typedef short bf16x8 __attribute__((ext_vector_type(8)));
typedef float f32x4  __attribute__((ext_vector_type(4)));

#define EPSF 1e-5f

// ---------------- workspace layout (float element offsets) — EXACT round-5/8/9/10 ----------------
#define OFF_P0   0          // 4,915,200 (conv ping)
#define OFF_U    1048576    //   409,600 (in P0 tail; conv3 out = 307,200 -> no overlap)
#define OFF_V    1572864    //   409,600
#define OFF_P1   4915200    // 1,228,800 (conv pong)
#define OFF_SS   6144000    // 384
#define OFF_SACC 6144384    // 96 (+pad)
#define OFF_Q    6144512    // 16,384
#define OFF_WP   6160896    // 196,608 float-slots: WP_hi + WP_lo bf16 frags
#define OFF_W1UV 6357504    // 13,312  (52 x 256)
#define OFF_W1Q  6370816    // 166,400 (650 x 256)
#define OFF_FW1T 6537216    // 65,536
#define OFF_FC2T 6602752    // 65,536
#define OFF_FC3T 6668288    // 32,768
#define OFF_XG   6701056    // 16,384
// end: 6,717,440 floats = 25.6 MiB

__device__ __forceinline__ unsigned short f2bf(float f) {
    union { float f; unsigned u; } cv; cv.f = f;
    const unsigned u = cv.u;
    return (unsigned short)((u + 0x7fffu + ((u >> 16) & 1u)) >> 16);  // RNE
}
__device__ __forceinline__ float bf2f(unsigned short h) {
    union { unsigned u; float f; } cv; cv.u = (unsigned)h << 16; return cv.f;
}

// ---------------- prep — EXACT round-5/8/9/10 ----------------
__global__ __launch_bounds__(256) void k_prep(
    const float* __restrict__ gw1, const float* __restrict__ gw234,
    const float* __restrict__ fw1, const float* __restrict__ fc2w,
    const float* __restrict__ fc3w, float* __restrict__ ws)
{
    int idx = blockIdx.x * 256 + threadIdx.x;
    if (idx < 16384) { ws[OFF_XG + idx] = 0.f; return; }
    idx -= 16384;
    if (idx < 96) { ws[OFF_SACC + idx] = 0.f; return; }
    idx -= 96;
    if (idx < 49152) {
        const int isLo = idx >= 24576;
        const int f = isLo ? idx - 24576 : idx;
        const int lane = f & 63;
        const int nt = (f >> 6) & 15;
        const int kb = (f >> 10) & 7;
        const int l  = f >> 13;
        const int o = nt * 16 + (lane & 15);
        const int k = kb * 32 + (lane >> 4) * 8;
        const float* src = gw234 + ((size_t)l * 256 + o) * 256 + k;
        unsigned short* dst = (unsigned short*)(ws + OFF_WP) + (size_t)idx * 8;
        #pragma unroll
        for (int j = 0; j < 8; ++j) {
            const float x = src[j];
            const unsigned short hi = f2bf(x);
            dst[j] = isLo ? f2bf(x - bf2f(hi)) : hi;
        }
        return;
    }
    idx -= 49152;
    if (idx < 13312) {
        const int o = idx & 255, k = idx >> 8;
        ws[OFF_W1UV + idx] = gw1[(size_t)o * 702 + k];
        return;
    }
    idx -= 13312;
    if (idx < 166400) {
        const int o = idx & 255, k = idx >> 8;
        ws[OFF_W1Q + idx] = gw1[(size_t)o * 702 + 52 + k];
        return;
    }
    idx -= 166400;
    if (idx < 65536) { const int o = idx & 255, k = idx >> 8; ws[OFF_FW1T + idx] = fw1[o * 256 + k];  return; }
    idx -= 65536;
    if (idx < 65536) { const int o = idx & 255, k = idx >> 8; ws[OFF_FC2T + idx] = fc2w[o * 256 + k]; return; }
    idx -= 65536;
    if (idx < 32768) { const int o = idx & 127, k = idx >> 7; ws[OFF_FC3T + idx] = fc3w[o * 256 + k]; return; }
}

// ---------------- conv layer 1 — LDS-tiled (modeled on proven k_convL) ----------------
// Block = (image b, 8-row tile ty of 5). Stage 3ch x 17 rows x 82 padded cols (16.7 KB)
// once; all 24 co consume from LDS. Weights repacked lw[(ci*9+tap)*24+co]; work item =
// (co, output-pixel-pair), co fastest.
__global__ __launch_bounds__(256) void k_convF(
    const float* __restrict__ img, const float* __restrict__ img2,
    const float* __restrict__ w, const float* __restrict__ bias,
    float* __restrict__ out)
{
    __shared__ float lds[3*17*82 + 648 + 24];   // 4854 floats = 19.4 KB
    float* lin   = lds;
    float* lw    = lds + 3*17*82;
    float* lbias = lw + 648;

    const int b  = blockIdx.x / 5;
    const int ty = blockIdx.x % 5;
    const int oy0 = ty * 8;
    const int t = threadIdx.x;

    for (int i = t; i < 648; i += 256) {
        const int co = i % 24, tap = (i / 24) % 9, ci = i / 216;
        lw[i] = w[(co*3 + ci)*9 + tap];
    }
    if (t < 24) lbias[t] = bias[t];

    const float* src = (b < 64 ? img : img2) + (size_t)(b & 63) * 3 * 6400;
    for (int i = t; i < 3*17*82; i += 256) {
        const int ci = i / (17*82);
        const int r  = i % (17*82);
        const int y  = r / 82, x = r % 82;
        const int gy = 2*oy0 - 1 + y, gx = x - 1;
        float v = 0.f;
        if (gy >= 0 && gy < 80 && gx >= 0 && gx < 80)
            v = src[ci*6400 + gy*80 + gx];
        lin[i] = v;
    }
    __syncthreads();

    const int NWI = 8 * 20 * 24;   // rows x col-pairs x co = 3840
    for (int wk = t; wk < NWI; wk += 256) {
        const int co = wk % 24;
        const int pr = wk / 24;
        const int i2 = (pr % 20) * 2;
        const int j  = pr / 20;
        float sA = lbias[co], sB = sA;
        const float* wp = lw + co;
        #pragma unroll
        for (int ci = 0; ci < 3; ++ci) {
            const int base = (ci*17 + 2*j)*82 + 2*i2;
            const float* wc = wp + ci * 216;
            #pragma unroll
            for (int kh = 0; kh < 3; ++kh) {
                const float* lr = lin + base + kh*82;
                const float2 fa = *(const float2*)lr;
                const float2 fb = *(const float2*)(lr + 2);
                const float  fc = lr[4];
                const float w0 = wc[(kh*3 + 0)*24];
                const float w1 = wc[(kh*3 + 1)*24];
                const float w2 = wc[(kh*3 + 2)*24];
                sA += fa.x*w0 + fa.y*w1 + fb.x*w2;
                sB += fb.x*w0 + fb.y*w1 + fc  *w2;
            }
        }
        const size_t o = (((size_t)b*24 + co)*40 + oy0 + j)*40 + i2;
        out[o]     = fmaxf(sA, 0.f);
        out[o + 1] = fmaxf(sB, 0.f);
    }
}

// ---------------- LDS-tiled conv, layers 2-4 — EXACT round-9/10 ----------------
__global__ __launch_bounds__(256) void k_convL(
    const float* __restrict__ in, const float* __restrict__ ss,
    const float* __restrict__ w, const float* __restrict__ bias,
    float* __restrict__ out, int IH, int IW, int OH, int OW, int TH, int nty)
{
    __shared__ float lds[14280];
    const int NR = 2*TH + 1, CSTR = IW + 2;
    float* lin   = lds;
    float* lw    = lds + 24 * NR * CSTR;
    float* lbias = lw + 5184;

    const int b  = blockIdx.x / nty;
    const int ty = blockIdx.x % nty;
    const int oy0 = ty * TH;
    const int t = threadIdx.x;

    for (int i = t; i < 5184; i += 256) {
        const int co = i % 24, tap = (i / 24) % 9, ci = i / 216;
        lw[i] = w[(co*24 + ci)*9 + tap];
    }
    if (t < 24) lbias[t] = bias[t];

    const float* sc = ss + (b >> 6) * 48;
    for (int i = t; i < 24 * NR * CSTR; i += 256) {
        const int ci = i / (NR * CSTR);
        const int r  = i % (NR * CSTR);
        const int y  = r / CSTR, x = r % CSTR;
        const int gy = 2*oy0 - 1 + y, gx = x - 1;
        float v = 0.f;
        if (gy >= 0 && gy < IH && gx >= 0 && gx < IW)
            v = in[(((size_t)b*24 + ci)*IH + gy)*IW + gx] * sc[ci] + sc[24 + ci];
        lin[i] = v;
    }
    __syncthreads();

    const int THe = min(TH, OH - oy0);
    const int PPR = (OW + 1) >> 1;
    const int NWI = THe * PPR * 24;
    for (int wk = t; wk < NWI; wk += 256) {
        const int co = wk % 24;
        const int pr = wk / 24;
        const int i2 = (pr % PPR) * 2;
        const int j  = pr / PPR;
        const bool hasB = (i2 + 1 < OW);
        float sA = lbias[co], sB = sA;
        const float* wp = lw + co;
        for (int ci = 0; ci < 24; ++ci) {
            const int base = (ci*NR + 2*j)*CSTR + 2*i2;
            const float* wc = wp + ci * 216;
            #pragma unroll
            for (int kh = 0; kh < 3; ++kh) {
                const float* lr = lin + base + kh*CSTR;
                const float2 fa = *(const float2*)lr;
                const float2 fb = *(const float2*)(lr + 2);
                const float  fc = hasB ? lr[4] : 0.f;
                const float w0 = wc[(kh*3 + 0)*24];
                const float w1 = wc[(kh*3 + 1)*24];
                const float w2 = wc[(kh*3 + 2)*24];
                sA += fa.x*w0 + fa.y*w1 + fb.x*w2;
                sB += fb.x*w0 + fb.y*w1 + fc  *w2;
            }
        }
        const size_t o = (((size_t)b*24 + co)*OH + oy0 + j)*OW + i2;
        out[o] = fmaxf(sA, 0.f);
        if (hasB) out[o + 1] = fmaxf(sB, 0.f);
    }
}

// ---------------- split-k BN stats (layer 1) — EXACT round-5/8/9/10 ----------------
__global__ __launch_bounds__(256) void k_stats_part(
    const float* __restrict__ y, float* __restrict__ sacc, int HW)
{
    const int img = blockIdx.x / (24*8);
    const int c   = (blockIdx.x / 8) % 24;
    const int sp  = blockIdx.x % 8;
    const int N = 64 * HW, chunk = N / 8;
    float sum = 0.f, sq = 0.f;
    for (int i = sp*chunk + threadIdx.x; i < (sp+1)*chunk; i += 256) {
        const int bb = i / HW, j = i - bb*HW;
        const float v = y[(size_t)((img*64 + bb)*24 + c) * HW + j];
        sum += v; sq += v*v;
    }
    #pragma unroll
    for (int off = 32; off > 0; off >>= 1) {
        sum += __shfl_down(sum, off);
        sq  += __shfl_down(sq, off);
    }
    __shared__ float red[8];
    const int lane = threadIdx.x & 63, wid = threadIdx.x >> 6;
    if (lane == 0) { red[wid] = sum; red[4 + wid] = sq; }
    __syncthreads();
    if (threadIdx.x == 0) {
        atomicAdd(&sacc[img*24 + c],      red[0]+red[1]+red[2]+red[3]);
        atomicAdd(&sacc[48 + img*24 + c], red[4]+red[5]+red[6]+red[7]);
    }
}

__global__ void k_stats_fin(const float* __restrict__ sacc, const float* __restrict__ g,
                            const float* __restrict__ beta, float* __restrict__ ss, int HW)
{
    const int t = threadIdx.x;
    if (t >= 48) return;
    const int img = t / 24, c = t % 24;
    const float N = 64.f * (float)HW;
    const float mean = sacc[t] / N;
    const float var  = sacc[48 + t] / N - mean*mean;
    const float scale = g[c] * rsqrtf(var + EPSF);
    ss[img*48 + c]      = scale;
    ss[img*48 + 24 + c] = beta[c] - mean * scale;
}

// ---------------- single-pass BN stats (layers 2-4) — EXACT round-5/8/9/10 ----------------
__global__ __launch_bounds__(256) void k_stats(
    const float* __restrict__ y, const float* __restrict__ g, const float* __restrict__ beta,
    float* __restrict__ ss, int HW)
{
    const int img = blockIdx.x / 24, c = blockIdx.x % 24;
    const int N = 64 * HW;
    float sum = 0.f, sq = 0.f;
    for (int i = threadIdx.x; i < N; i += 256) {
        const int bb = i / HW, j = i - bb*HW;
        const float v = y[(size_t)((img*64 + bb)*24 + c) * HW + j];
        sum += v; sq += v*v;
    }
    #pragma unroll
    for (int off = 32; off > 0; off >>= 1) {
        sum += __shfl_down(sum, off);
        sq  += __shfl_down(sq, off);
    }
    __shared__ float red[8];
    const int lane = threadIdx.x & 63, wid = threadIdx.x >> 6;
    if (lane == 0) { red[wid] = sum; red[4 + wid] = sq; }
    __syncthreads();
    if (threadIdx.x == 0) {
        const float S  = red[0]+red[1]+red[2]+red[3];
        const float Q2 = red[4]+red[5]+red[6]+red[7];
        const float mean = S / (float)N;
        const float var  = Q2 / (float)N - mean*mean;
        const float scale = g[c] * rsqrtf(var + EPSF);
        ss[img*48 + c]      = scale;
        ss[img*48 + 24 + c] = beta[c] - mean * scale;
    }
}

// ---------------- U,V — EXACT round-5/8/9/10 ----------------
__global__ __launch_bounds__(256) void k_uv(
    const float* __restrict__ P1, const float* __restrict__ SS4,
    const float* __restrict__ w1uvT, float* __restrict__ Ub, float* __restrict__ Vb)
{
    __shared__ float f[26];
    const int row = blockIdx.x;           // b*25+cell, b<64 (img1)
    const int b = row / 25, cell = row % 25;
    const int t = threadIdx.x;
    if (t < 26) {
        float v;
        if (t < 24)      v = P1[((size_t)(b*24 + t))*25 + cell] * SS4[t] + SS4[24 + t];
        else if (t == 24) v = ((float)cell / 5.f - 2.f) * 0.5f;
        else              v = ((float)(cell % 5) - 2.f) * 0.5f;
        f[t] = v;
    }
    __syncthreads();
    float su = 0.f, sv = 0.f;
    #pragma unroll
    for (int k = 0; k < 26; ++k) {
        su += f[k] * w1uvT[k*256 + t];
        sv += f[k] * w1uvT[(26 + k)*256 + t];
    }
    Ub[(size_t)row*256 + t] = su;
    Vb[(size_t)row*256 + t] = sv;
}

// ---------------- Q — unroll 10 for load ILP (latency-bound GEMV) ----------------
__global__ __launch_bounds__(256) void k_q(
    const float* __restrict__ P1, const float* __restrict__ SS4,
    const float* __restrict__ w1qT, const float* __restrict__ gb, float* __restrict__ Qb)
{
    __shared__ float f[650];
    const int b = blockIdx.x, t = threadIdx.x;
    for (int i = t; i < 650; i += 256) {
        const int cell = i / 26, ff = i % 26;
        float v;
        if (ff < 24)      v = P1[((size_t)((64 + b)*24 + ff))*25 + cell] * SS4[48 + ff] + SS4[72 + ff];
        else if (ff == 24) v = ((float)cell / 5.f - 2.f) * 0.5f;
        else               v = ((float)(cell % 5) - 2.f) * 0.5f;
        f[i] = v;
    }
    __syncthreads();
    float s = gb[t];
    #pragma unroll 10
    for (int k = 0; k < 650; ++k) s += f[k] * w1qT[k*256 + t];
    Qb[b*256 + t] = s;
}

// ---------------- MFMA g-MLP (bf16x3) + sum pool — col-stripe + weight SW pipeline ----------------
// Round-11 change: double-buffered weight prefetch in named register sets (wah/wal vs
// wbh/wbl; rule #20: all register-array indices compile-time). 2 kb per iteration:
// prefetch W(kb+1) -> MFMA(kb) -> prefetch W(kb+2) -> MFMA(kb+1). With only 2 waves/SIMD
// (LDS-capped), ILP must hide the ~250cy L2 weight-load latency that TLP can't.
// Accumulation order unchanged -> bitwise-identical output.
__global__ __launch_bounds__(256) void k_gmlp(
    const float* __restrict__ U, const float* __restrict__ V, const float* __restrict__ Q,
    const unsigned short* __restrict__ WP, const float* __restrict__ gb, float* __restrict__ xg)
{
    __shared__ unsigned short hhi[16384];   // 64x256 bf16 = 32 KB
    __shared__ unsigned short hlo[16384];
    const int b    = blockIdx.x / 10;
    const int row0 = (blockIdx.x % 10) * 64;
    const int tid  = threadIdx.x;
    const int lane = tid & 63, w = tid >> 6;
    const int w4 = w * 4;

    // layer 1 fill: wave fills rows [w*16, w*16+16)
    {
        const int r0 = w * 16;
        const float2* Q2 = (const float2*)(Q + b*256);
        const float2 q0 = Q2[lane], q1 = Q2[64 + lane];
        for (int rr = 0; rr < 16; ++rr) {
            const int row = r0 + rr;
            int p = row0 + row; if (p > 624) p = 624;
            const float2* u2p = (const float2*)(U + ((size_t)(b*25 + p % 25)) * 256);
            const float2* v2p = (const float2*)(V + ((size_t)(b*25 + p / 25)) * 256);
            #pragma unroll
            for (int cc = 0; cc < 2; ++cc) {
                const int cp = cc*64 + lane;
                const float2 u2 = u2p[cp], v2 = v2p[cp];
                const float2 q2 = cc ? q1 : q0;
                const float x0 = fmaxf(u2.x + v2.x + q2.x, 0.f);
                const float x1 = fmaxf(u2.y + v2.y + q2.y, 0.f);
                const unsigned short h0 = f2bf(x0), h1 = f2bf(x1);
                const float l0 = x0 - bf2f(h0), l1 = x1 - bf2f(h1);
                const int byte = (row*512 + cp*4) ^ ((row & 7) << 4);
                *(unsigned*)((char*)hhi + byte) = (unsigned)h0 | ((unsigned)h1 << 16);
                *(unsigned*)((char*)hlo + byte) = (unsigned)f2bf(l0) | ((unsigned)f2bf(l1) << 16);
            }
        }
    }
    __syncthreads();

    const bf16x8* WPB = (const bf16x8*)WP;
    f32x4 acc[4][4];   // [rowset][n]
    #pragma unroll 1
    for (int l = 0; l < 3; ++l) {
        #pragma unroll
        for (int rs = 0; rs < 4; ++rs)
            #pragma unroll
            for (int n = 0; n < 4; ++n) acc[rs][n] = (f32x4)0.f;

        bf16x8 wah[4], wal[4], wbh[4], wbl[4];
        #pragma unroll
        for (int n = 0; n < 4; ++n) {
            const bf16x8* p = WPB + ((size_t)((l*8 + 0)*16 + w4 + n))*64 + lane;
            wah[n] = p[0]; wal[n] = p[24576];
        }

        #pragma unroll 1
        for (int kb2 = 0; kb2 < 4; ++kb2) {
            const int kb = kb2 * 2;
            // prefetch W(kb+1) into wb
            #pragma unroll
            for (int n = 0; n < 4; ++n) {
                const bf16x8* p = WPB + ((size_t)((l*8 + kb + 1)*16 + w4 + n))*64 + lane;
                wbh[n] = p[0]; wbl[n] = p[24576];
            }
            // A(kb) + MFMA with wa
            {
                bf16x8 ahi[4], alo[4];
                #pragma unroll
                for (int rs = 0; rs < 4; ++rs) {
                    const int ar = rs*16 + (lane & 15);
                    const int off = (ar*512 + kb*64 + (lane >> 4)*16) ^ ((ar & 7) << 4);
                    ahi[rs] = *(const bf16x8*)((char*)hhi + off);
                    alo[rs] = *(const bf16x8*)((char*)hlo + off);
                }
                #pragma unroll
                for (int n = 0; n < 4; ++n) {
                    #pragma unroll
                    for (int rs = 0; rs < 4; ++rs) {
                        acc[rs][n] = __builtin_amdgcn_mfma_f32_16x16x32_bf16(ahi[rs], wah[n], acc[rs][n], 0, 0, 0);
                        acc[rs][n] = __builtin_amdgcn_mfma_f32_16x16x32_bf16(ahi[rs], wal[n], acc[rs][n], 0, 0, 0);
                        acc[rs][n] = __builtin_amdgcn_mfma_f32_16x16x32_bf16(alo[rs], wah[n], acc[rs][n], 0, 0, 0);
                    }
                }
            }
            // prefetch W(kb+2) into wa (last iteration: none)
            if (kb2 < 3) {
                #pragma unroll
                for (int n = 0; n < 4; ++n) {
                    const bf16x8* p = WPB + ((size_t)((l*8 + kb + 2)*16 + w4 + n))*64 + lane;
                    wah[n] = p[0]; wal[n] = p[24576];
                }
            }
            // A(kb+1) + MFMA with wb
            {
                bf16x8 ahi[4], alo[4];
                #pragma unroll
                for (int rs = 0; rs < 4; ++rs) {
                    const int ar = rs*16 + (lane & 15);
                    const int off = (ar*512 + (kb + 1)*64 + (lane >> 4)*16) ^ ((ar & 7) << 4);
                    ahi[rs] = *(const bf16x8*)((char*)hhi + off);
                    alo[rs] = *(const bf16x8*)((char*)hlo + off);
                }
                #pragma unroll
                for (int n = 0; n < 4; ++n) {
                    #pragma unroll
                    for (int rs = 0; rs < 4; ++rs) {
                        acc[rs][n] = __builtin_amdgcn_mfma_f32_16x16x32_bf16(ahi[rs], wbh[n], acc[rs][n], 0, 0, 0);
                        acc[rs][n] = __builtin_amdgcn_mfma_f32_16x16x32_bf16(ahi[rs], wbl[n], acc[rs][n], 0, 0, 0);
                        acc[rs][n] = __builtin_amdgcn_mfma_f32_16x16x32_bf16(alo[rs], wbh[n], acc[rs][n], 0, 0, 0);
                    }
                }
            }
        }
        __syncthreads();   // all reads of h done before overwrite
        if (l < 2) {
            #pragma unroll
            for (int n = 0; n < 4; ++n) {
                const int col = (w4 + n)*16 + (lane & 15);
                const float bias = gb[(l+1)*256 + col];
                #pragma unroll
                for (int rs = 0; rs < 4; ++rs) {
                    #pragma unroll
                    for (int r = 0; r < 4; ++r) {
                        const int row = rs*16 + 4*(lane >> 4) + r;
                        const float v = fmaxf(acc[rs][n][r] + bias, 0.f);
                        const unsigned short hv = f2bf(v);
                        const float lv = v - bf2f(hv);
                        const int byte = (row*512 + col*2) ^ ((row & 7) << 4);
                        *(unsigned short*)((char*)hhi + byte) = hv;
                        *(unsigned short*)((char*)hlo + byte) = f2bf(lv);
                    }
                }
            }
            __syncthreads();
        } else {
            #pragma unroll
            for (int n = 0; n < 4; ++n) {
                const int col = (w4 + n)*16 + (lane & 15);
                const float bias = gb[3*256 + col];
                float s = 0.f;
                #pragma unroll
                for (int rs = 0; rs < 4; ++rs) {
                    #pragma unroll
                    for (int r = 0; r < 4; ++r) {
                        const int row = rs*16 + 4*(lane >> 4) + r;
                        if (row0 + row < 625) s += fmaxf(acc[rs][n][r] + bias, 0.f);
                    }
                }
                s += __shfl_xor(s, 16);
                s += __shfl_xor(s, 32);
                if (lane < 16) atomicAdd(&xg[b*256 + col], s);
            }
        }
    }
}

// ---------------- fused head — unroll 8 for load ILP ----------------
__global__ __launch_bounds__(256) void k_head(
    const float* __restrict__ XG, const float* __restrict__ fw1T, const float* __restrict__ fb1,
    const float* __restrict__ fc2T, const float* __restrict__ fc2b,
    const float* __restrict__ fc3T, const float* __restrict__ fc3b, float* __restrict__ out)
{
    __shared__ float xa[256], xb[256], ys[128];
    const int b = blockIdx.x, t = threadIdx.x;
    xa[t] = XG[b*256 + t];
    __syncthreads();
    float s = fb1[t];
    #pragma unroll 8
    for (int k = 0; k < 256; ++k) s += xa[k] * fw1T[k*256 + t];
    xb[t] = fmaxf(s, 0.f);
    __syncthreads();
    s = fc2b[t];
    #pragma unroll 8
    for (int k = 0; k < 256; ++k) s += xb[k] * fc2T[k*256 + t];
    xa[t] = fmaxf(s, 0.f);
    __syncthreads();
    if (t < 128) {
        s = fc3b[t];
        #pragma unroll 8
        for (int k = 0; k < 256; ++k) s += xa[k] * fc3T[k*128 + t];
        ys[t] = s;
    }
    __syncthreads();
    if (t < 16) {
        float m = ys[t*8];
        #pragma unroll
        for (int i = 1; i < 8; ++i) m = fmaxf(m, ys[t*8 + i]);
        float e[8], sum = 0.f;
        #pragma unroll
        for (int i = 0; i < 8; ++i) { e[i] = expf(ys[t*8 + i] - m); sum += e[i]; }
        const float inv = 1.f / sum;
        #pragma unroll
        for (int i = 0; i < 8; ++i) out[b*128 + t*8 + i] = fmaxf(e[i]*inv, 0.001f);
    }
}

extern "C" void kernel_launch(void* const* d_in, const int* in_sizes, int n_in,
                              void* d_out, int out_size, void* d_ws, size_t ws_size,
                              hipStream_t stream)
{
    const float* img   = (const float*)d_in[0];
    const float* img2  = (const float*)d_in[1];
    const float* cw1   = (const float*)d_in[2];
    const float* cw234 = (const float*)d_in[3];
    const float* cb    = (const float*)d_in[4];
    const float* bng   = (const float*)d_in[5];
    const float* bnb   = (const float*)d_in[6];
    const float* gw1   = (const float*)d_in[7];
    const float* gw234 = (const float*)d_in[8];
    const float* gb    = (const float*)d_in[9];
    const float* fw1   = (const float*)d_in[10];
    const float* fb1   = (const float*)d_in[11];
    const float* fc2w  = (const float*)d_in[12];
    const float* fc2b  = (const float*)d_in[13];
    const float* fc3w  = (const float*)d_in[14];
    const float* fc3b  = (const float*)d_in[15];

    float* ws = (float*)d_ws;
    float* P0 = ws + OFF_P0;  float* P1 = ws + OFF_P1;   float* SS  = ws + OFF_SS;
    float* SA = ws + OFF_SACC; float* Ub = ws + OFF_U;   float* Vb  = ws + OFF_V;
    float* Qb = ws + OFF_Q;
    unsigned short* WP = (unsigned short*)(ws + OFF_WP);
    float* W1UV = ws + OFF_W1UV; float* W1Q = ws + OFF_W1Q;
    float* FW1T = ws + OFF_FW1T; float* FC2T = ws + OFF_FC2T; float* FC3T = ws + OFF_FC3T;
    float* XG = ws + OFF_XG;
    float* out = (float*)d_out;

    hipLaunchKernelGGL(k_prep, dim3(1599), dim3(256), 0, stream, gw1, gw234, fw1, fc2w, fc3w, ws);

    // conv1: LDS-tiled, 128 imgs x 5 row-tiles
    hipLaunchKernelGGL(k_convF, dim3(640), dim3(256), 0, stream, img, img2, cw1, cb, P0);
    hipLaunchKernelGGL(k_stats_part, dim3(384), dim3(256), 0, stream, P0, SA, 1600);
    hipLaunchKernelGGL(k_stats_fin,  dim3(1),   dim3(64),  0, stream, SA, bng, bnb, SS, 1600);
    // conv2: 40x40 -> 20x20; TH=4, nty=5
    hipLaunchKernelGGL(k_convL, dim3(640), dim3(256), 0, stream,
                       P0, SS, cw234, cb + 24, P1, 40, 40, 20, 20, 4, 5);
    hipLaunchKernelGGL(k_stats, dim3(48), dim3(256), 0, stream, P1, bng+24, bnb+24, SS+96, 400);
    // conv3: 20x20 -> 10x10; TH=5, nty=2
    hipLaunchKernelGGL(k_convL, dim3(256), dim3(256), 0, stream,
                       P1, SS + 96, cw234 + 5184, cb + 48, P0, 20, 20, 10, 10, 5, 2);
    hipLaunchKernelGGL(k_stats, dim3(48), dim3(256), 0, stream, P0, bng+48, bnb+48, SS+192, 100);
    // conv4: 10x10 -> 5x5; TH=5, nty=1
    hipLaunchKernelGGL(k_convL, dim3(128), dim3(256), 0, stream,
                       P0, SS + 192, cw234 + 10368, cb + 72, P1, 10, 10, 5, 5, 5, 1);
    hipLaunchKernelGGL(k_stats, dim3(48), dim3(256), 0, stream, P1, bng+72, bnb+72, SS+288, 25);

    hipLaunchKernelGGL(k_uv, dim3(1600), dim3(256), 0, stream, P1, SS+288, W1UV, Ub, Vb);
    hipLaunchKernelGGL(k_q,  dim3(64),   dim3(256), 0, stream, P1, SS+288, W1Q, gb, Qb);

    hipLaunchKernelGGL(k_gmlp, dim3(640), dim3(256), 0, stream, Ub, Vb, Qb, WP, gb, XG);

    hipLaunchKernelGGL(k_head, dim3(64), dim3(256), 0, stream,
                       XG, FW1T, fb1, FC2T, fc2b, FC3T, fc3b, out);
}

// Round 12
// 330.374 us; speedup vs baseline: 2.6480x; 1.0910x over previous
//
#include <hip/hip_runtime.h>

typedef short bf16x8 __attribute__((ext_vector_type(8)));
typedef float f32x4  __attribute__((ext_vector_type(4)));

#define EPSF 1e-5f

// ---------------- workspace layout (float element offsets) — EXACT round-5..11 ----------------
#define OFF_P0   0          // 4,915,200 (conv ping)
#define OFF_U    1048576    //   409,600 (in P0 tail; conv3 out = 307,200 -> no overlap)
#define OFF_V    1572864    //   409,600
#define OFF_P1   4915200    // 1,228,800 (conv pong)
#define OFF_SS   6144000    // 384
#define OFF_SACC 6144384    // 96 (+pad)
#define OFF_Q    6144512    // 16,384
#define OFF_WP   6160896    // 196,608 float-slots: WP_hi + WP_lo bf16 frags
#define OFF_W1UV 6357504    // 13,312  (52 x 256)
#define OFF_W1Q  6370816    // 166,400 (650 x 256)
#define OFF_FW1T 6537216    // 65,536
#define OFF_FC2T 6602752    // 65,536
#define OFF_FC3T 6668288    // 32,768
#define OFF_XG   6701056    // 16,384
// end: 6,717,440 floats = 25.6 MiB

__device__ __forceinline__ unsigned short f2bf(float f) {
    union { float f; unsigned u; } cv; cv.f = f;
    const unsigned u = cv.u;
    return (unsigned short)((u + 0x7fffu + ((u >> 16) & 1u)) >> 16);  // RNE
}
__device__ __forceinline__ float bf2f(unsigned short h) {
    union { unsigned u; float f; } cv; cv.u = (unsigned)h << 16; return cv.f;
}

// ---------------- prep — EXACT round-5..11 ----------------
__global__ __launch_bounds__(256) void k_prep(
    const float* __restrict__ gw1, const float* __restrict__ gw234,
    const float* __restrict__ fw1, const float* __restrict__ fc2w,
    const float* __restrict__ fc3w, float* __restrict__ ws)
{
    int idx = blockIdx.x * 256 + threadIdx.x;
    if (idx < 16384) { ws[OFF_XG + idx] = 0.f; return; }
    idx -= 16384;
    if (idx < 96) { ws[OFF_SACC + idx] = 0.f; return; }
    idx -= 96;
    if (idx < 49152) {
        const int isLo = idx >= 24576;
        const int f = isLo ? idx - 24576 : idx;
        const int lane = f & 63;
        const int nt = (f >> 6) & 15;
        const int kb = (f >> 10) & 7;
        const int l  = f >> 13;
        const int o = nt * 16 + (lane & 15);
        const int k = kb * 32 + (lane >> 4) * 8;
        const float* src = gw234 + ((size_t)l * 256 + o) * 256 + k;
        unsigned short* dst = (unsigned short*)(ws + OFF_WP) + (size_t)idx * 8;
        #pragma unroll
        for (int j = 0; j < 8; ++j) {
            const float x = src[j];
            const unsigned short hi = f2bf(x);
            dst[j] = isLo ? f2bf(x - bf2f(hi)) : hi;
        }
        return;
    }
    idx -= 49152;
    if (idx < 13312) {
        const int o = idx & 255, k = idx >> 8;
        ws[OFF_W1UV + idx] = gw1[(size_t)o * 702 + k];
        return;
    }
    idx -= 13312;
    if (idx < 166400) {
        const int o = idx & 255, k = idx >> 8;
        ws[OFF_W1Q + idx] = gw1[(size_t)o * 702 + 52 + k];
        return;
    }
    idx -= 166400;
    if (idx < 65536) { const int o = idx & 255, k = idx >> 8; ws[OFF_FW1T + idx] = fw1[o * 256 + k];  return; }
    idx -= 65536;
    if (idx < 65536) { const int o = idx & 255, k = idx >> 8; ws[OFF_FC2T + idx] = fc2w[o * 256 + k]; return; }
    idx -= 65536;
    if (idx < 32768) { const int o = idx & 127, k = idx >> 7; ws[OFF_FC3T + idx] = fc3w[o * 256 + k]; return; }
}

// ---------------- conv layer 1 — LDS-tiled — EXACT round-11 ----------------
__global__ __launch_bounds__(256) void k_convF(
    const float* __restrict__ img, const float* __restrict__ img2,
    const float* __restrict__ w, const float* __restrict__ bias,
    float* __restrict__ out)
{
    __shared__ float lds[3*17*82 + 648 + 24];   // 4854 floats = 19.4 KB
    float* lin   = lds;
    float* lw    = lds + 3*17*82;
    float* lbias = lw + 648;

    const int b  = blockIdx.x / 5;
    const int ty = blockIdx.x % 5;
    const int oy0 = ty * 8;
    const int t = threadIdx.x;

    for (int i = t; i < 648; i += 256) {
        const int co = i % 24, tap = (i / 24) % 9, ci = i / 216;
        lw[i] = w[(co*3 + ci)*9 + tap];
    }
    if (t < 24) lbias[t] = bias[t];

    const float* src = (b < 64 ? img : img2) + (size_t)(b & 63) * 3 * 6400;
    for (int i = t; i < 3*17*82; i += 256) {
        const int ci = i / (17*82);
        const int r  = i % (17*82);
        const int y  = r / 82, x = r % 82;
        const int gy = 2*oy0 - 1 + y, gx = x - 1;
        float v = 0.f;
        if (gy >= 0 && gy < 80 && gx >= 0 && gx < 80)
            v = src[ci*6400 + gy*80 + gx];
        lin[i] = v;
    }
    __syncthreads();

    const int NWI = 8 * 20 * 24;   // rows x col-pairs x co = 3840
    for (int wk = t; wk < NWI; wk += 256) {
        const int co = wk % 24;
        const int pr = wk / 24;
        const int i2 = (pr % 20) * 2;
        const int j  = pr / 20;
        float sA = lbias[co], sB = sA;
        const float* wp = lw + co;
        #pragma unroll
        for (int ci = 0; ci < 3; ++ci) {
            const int base = (ci*17 + 2*j)*82 + 2*i2;
            const float* wc = wp + ci * 216;
            #pragma unroll
            for (int kh = 0; kh < 3; ++kh) {
                const float* lr = lin + base + kh*82;
                const float2 fa = *(const float2*)lr;
                const float2 fb = *(const float2*)(lr + 2);
                const float  fc = lr[4];
                const float w0 = wc[(kh*3 + 0)*24];
                const float w1 = wc[(kh*3 + 1)*24];
                const float w2 = wc[(kh*3 + 2)*24];
                sA += fa.x*w0 + fa.y*w1 + fb.x*w2;
                sB += fb.x*w0 + fb.y*w1 + fc  *w2;
            }
        }
        const size_t o = (((size_t)b*24 + co)*40 + oy0 + j)*40 + i2;
        out[o]     = fmaxf(sA, 0.f);
        out[o + 1] = fmaxf(sB, 0.f);
    }
}

// ---------------- LDS-tiled conv, layers 2-4 — EXACT round-9/10/11 ----------------
__global__ __launch_bounds__(256) void k_convL(
    const float* __restrict__ in, const float* __restrict__ ss,
    const float* __restrict__ w, const float* __restrict__ bias,
    float* __restrict__ out, int IH, int IW, int OH, int OW, int TH, int nty)
{
    __shared__ float lds[14280];
    const int NR = 2*TH + 1, CSTR = IW + 2;
    float* lin   = lds;
    float* lw    = lds + 24 * NR * CSTR;
    float* lbias = lw + 5184;

    const int b  = blockIdx.x / nty;
    const int ty = blockIdx.x % nty;
    const int oy0 = ty * TH;
    const int t = threadIdx.x;

    for (int i = t; i < 5184; i += 256) {
        const int co = i % 24, tap = (i / 24) % 9, ci = i / 216;
        lw[i] = w[(co*24 + ci)*9 + tap];
    }
    if (t < 24) lbias[t] = bias[t];

    const float* sc = ss + (b >> 6) * 48;
    for (int i = t; i < 24 * NR * CSTR; i += 256) {
        const int ci = i / (NR * CSTR);
        const int r  = i % (NR * CSTR);
        const int y  = r / CSTR, x = r % CSTR;
        const int gy = 2*oy0 - 1 + y, gx = x - 1;
        float v = 0.f;
        if (gy >= 0 && gy < IH && gx >= 0 && gx < IW)
            v = in[(((size_t)b*24 + ci)*IH + gy)*IW + gx] * sc[ci] + sc[24 + ci];
        lin[i] = v;
    }
    __syncthreads();

    const int THe = min(TH, OH - oy0);
    const int PPR = (OW + 1) >> 1;
    const int NWI = THe * PPR * 24;
    for (int wk = t; wk < NWI; wk += 256) {
        const int co = wk % 24;
        const int pr = wk / 24;
        const int i2 = (pr % PPR) * 2;
        const int j  = pr / PPR;
        const bool hasB = (i2 + 1 < OW);
        float sA = lbias[co], sB = sA;
        const float* wp = lw + co;
        for (int ci = 0; ci < 24; ++ci) {
            const int base = (ci*NR + 2*j)*CSTR + 2*i2;
            const float* wc = wp + ci * 216;
            #pragma unroll
            for (int kh = 0; kh < 3; ++kh) {
                const float* lr = lin + base + kh*CSTR;
                const float2 fa = *(const float2*)lr;
                const float2 fb = *(const float2*)(lr + 2);
                const float  fc = hasB ? lr[4] : 0.f;
                const float w0 = wc[(kh*3 + 0)*24];
                const float w1 = wc[(kh*3 + 1)*24];
                const float w2 = wc[(kh*3 + 2)*24];
                sA += fa.x*w0 + fa.y*w1 + fb.x*w2;
                sB += fb.x*w0 + fb.y*w1 + fc  *w2;
            }
        }
        const size_t o = (((size_t)b*24 + co)*OH + oy0 + j)*OW + i2;
        out[o] = fmaxf(sA, 0.f);
        if (hasB) out[o + 1] = fmaxf(sB, 0.f);
    }
}

// ---------------- split-k BN stats (layer 1) — EXACT round-5..11 ----------------
__global__ __launch_bounds__(256) void k_stats_part(
    const float* __restrict__ y, float* __restrict__ sacc, int HW)
{
    const int img = blockIdx.x / (24*8);
    const int c   = (blockIdx.x / 8) % 24;
    const int sp  = blockIdx.x % 8;
    const int N = 64 * HW, chunk = N / 8;
    float sum = 0.f, sq = 0.f;
    for (int i = sp*chunk + threadIdx.x; i < (sp+1)*chunk; i += 256) {
        const int bb = i / HW, j = i - bb*HW;
        const float v = y[(size_t)((img*64 + bb)*24 + c) * HW + j];
        sum += v; sq += v*v;
    }
    #pragma unroll
    for (int off = 32; off > 0; off >>= 1) {
        sum += __shfl_down(sum, off);
        sq  += __shfl_down(sq, off);
    }
    __shared__ float red[8];
    const int lane = threadIdx.x & 63, wid = threadIdx.x >> 6;
    if (lane == 0) { red[wid] = sum; red[4 + wid] = sq; }
    __syncthreads();
    if (threadIdx.x == 0) {
        atomicAdd(&sacc[img*24 + c],      red[0]+red[1]+red[2]+red[3]);
        atomicAdd(&sacc[48 + img*24 + c], red[4]+red[5]+red[6]+red[7]);
    }
}

__global__ void k_stats_fin(const float* __restrict__ sacc, const float* __restrict__ g,
                            const float* __restrict__ beta, float* __restrict__ ss, int HW)
{
    const int t = threadIdx.x;
    if (t >= 48) return;
    const int img = t / 24, c = t % 24;
    const float N = 64.f * (float)HW;
    const float mean = sacc[t] / N;
    const float var  = sacc[48 + t] / N - mean*mean;
    const float scale = g[c] * rsqrtf(var + EPSF);
    ss[img*48 + c]      = scale;
    ss[img*48 + 24 + c] = beta[c] - mean * scale;
}

// ---------------- single-pass BN stats (layers 2-4) — EXACT round-5..11 ----------------
__global__ __launch_bounds__(256) void k_stats(
    const float* __restrict__ y, const float* __restrict__ g, const float* __restrict__ beta,
    float* __restrict__ ss, int HW)
{
    const int img = blockIdx.x / 24, c = blockIdx.x % 24;
    const int N = 64 * HW;
    float sum = 0.f, sq = 0.f;
    for (int i = threadIdx.x; i < N; i += 256) {
        const int bb = i / HW, j = i - bb*HW;
        const float v = y[(size_t)((img*64 + bb)*24 + c) * HW + j];
        sum += v; sq += v*v;
    }
    #pragma unroll
    for (int off = 32; off > 0; off >>= 1) {
        sum += __shfl_down(sum, off);
        sq  += __shfl_down(sq, off);
    }
    __shared__ float red[8];
    const int lane = threadIdx.x & 63, wid = threadIdx.x >> 6;
    if (lane == 0) { red[wid] = sum; red[4 + wid] = sq; }
    __syncthreads();
    if (threadIdx.x == 0) {
        const float S  = red[0]+red[1]+red[2]+red[3];
        const float Q2 = red[4]+red[5]+red[6]+red[7];
        const float mean = S / (float)N;
        const float var  = Q2 / (float)N - mean*mean;
        const float scale = g[c] * rsqrtf(var + EPSF);
        ss[img*48 + c]      = scale;
        ss[img*48 + 24 + c] = beta[c] - mean * scale;
    }
}

// ---------------- fused U,V + Q (round-11 bodies, one dispatch) ----------------
__global__ __launch_bounds__(256) void k_uvq(
    const float* __restrict__ P1, const float* __restrict__ SS4,
    const float* __restrict__ w1uvT, const float* __restrict__ w1qT,
    const float* __restrict__ gb,
    float* __restrict__ Ub, float* __restrict__ Vb, float* __restrict__ Qb)
{
    __shared__ float f[650];
    const int t = threadIdx.x;
    if (blockIdx.x < 1600) {
        const int row = blockIdx.x;           // b*25+cell, b<64 (img1)
        const int b = row / 25, cell = row % 25;
        if (t < 26) {
            float v;
            if (t < 24)      v = P1[((size_t)(b*24 + t))*25 + cell] * SS4[t] + SS4[24 + t];
            else if (t == 24) v = ((float)cell / 5.f - 2.f) * 0.5f;
            else              v = ((float)(cell % 5) - 2.f) * 0.5f;
            f[t] = v;
        }
        __syncthreads();
        float su = 0.f, sv = 0.f;
        #pragma unroll
        for (int k = 0; k < 26; ++k) {
            su += f[k] * w1uvT[k*256 + t];
            sv += f[k] * w1uvT[(26 + k)*256 + t];
        }
        Ub[(size_t)row*256 + t] = su;
        Vb[(size_t)row*256 + t] = sv;
    } else {
        const int b = blockIdx.x - 1600;
        for (int i = t; i < 650; i += 256) {
            const int cell = i / 26, ff = i % 26;
            float v;
            if (ff < 24)      v = P1[((size_t)((64 + b)*24 + ff))*25 + cell] * SS4[48 + ff] + SS4[72 + ff];
            else if (ff == 24) v = ((float)cell / 5.f - 2.f) * 0.5f;
            else               v = ((float)(cell % 5) - 2.f) * 0.5f;
            f[i] = v;
        }
        __syncthreads();
        float s = gb[t];
        #pragma unroll 10
        for (int k = 0; k < 650; ++k) s += f[k] * w1qT[k*256 + t];
        Qb[b*256 + t] = s;
    }
}

// ---------------- MFMA g-MLP (bf16x3) + sum pool — 32-row tiles, 16 waves/CU ----------------
// Round-12 change: tile 64->32 rows (grid 1280 = 64 b x 20 tiles), LDS 64->32 KB,
// acc [2][4] (32 VGPR), weight dbuf dropped, __launch_bounds__(256,4) pins VGPR<=128
// -> 4 blocks/CU x 4 waves = 16 waves/CU (was 8). TLP replaces the r11 ILP pipeline
// for hiding per-kb L2 weight latency. MFMA order per output unchanged.
__global__ __launch_bounds__(256, 4) void k_gmlp(
    const float* __restrict__ U, const float* __restrict__ V, const float* __restrict__ Q,
    const unsigned short* __restrict__ WP, const float* __restrict__ gb, float* __restrict__ xg)
{
    __shared__ unsigned short hhi[8192];   // 32x256 bf16 = 16 KB
    __shared__ unsigned short hlo[8192];
    const int b    = blockIdx.x / 20;
    const int row0 = (blockIdx.x % 20) * 32;
    const int tid  = threadIdx.x;
    const int lane = tid & 63, w = tid >> 6;
    const int w4 = w * 4;

    // layer 1 fill: wave fills rows [w*8, w*8+8)
    {
        const int r0 = w * 8;
        const float2* Q2 = (const float2*)(Q + b*256);
        const float2 q0 = Q2[lane], q1 = Q2[64 + lane];
        for (int rr = 0; rr < 8; ++rr) {
            const int row = r0 + rr;
            int p = row0 + row; if (p > 624) p = 624;
            const float2* u2p = (const float2*)(U + ((size_t)(b*25 + p % 25)) * 256);
            const float2* v2p = (const float2*)(V + ((size_t)(b*25 + p / 25)) * 256);
            #pragma unroll
            for (int cc = 0; cc < 2; ++cc) {
                const int cp = cc*64 + lane;
                const float2 u2 = u2p[cp], v2 = v2p[cp];
                const float2 q2 = cc ? q1 : q0;
                const float x0 = fmaxf(u2.x + v2.x + q2.x, 0.f);
                const float x1 = fmaxf(u2.y + v2.y + q2.y, 0.f);
                const unsigned short h0 = f2bf(x0), h1 = f2bf(x1);
                const float l0 = x0 - bf2f(h0), l1 = x1 - bf2f(h1);
                const int byte = (row*512 + cp*4) ^ ((row & 7) << 4);
                *(unsigned*)((char*)hhi + byte) = (unsigned)h0 | ((unsigned)h1 << 16);
                *(unsigned*)((char*)hlo + byte) = (unsigned)f2bf(l0) | ((unsigned)f2bf(l1) << 16);
            }
        }
    }
    __syncthreads();

    const bf16x8* WPB = (const bf16x8*)WP;
    f32x4 acc[2][4];   // [rowset][n]
    #pragma unroll 1
    for (int l = 0; l < 3; ++l) {
        #pragma unroll
        for (int rs = 0; rs < 2; ++rs)
            #pragma unroll
            for (int n = 0; n < 4; ++n) acc[rs][n] = (f32x4)0.f;

        #pragma unroll 1
        for (int kb = 0; kb < 8; ++kb) {
            bf16x8 wh[4], wl[4];
            #pragma unroll
            for (int n = 0; n < 4; ++n) {
                const bf16x8* p = WPB + ((size_t)((l*8 + kb)*16 + w4 + n))*64 + lane;
                wh[n] = p[0]; wl[n] = p[24576];   // lo copy: +24576 fragments
            }
            bf16x8 ahi[2], alo[2];
            #pragma unroll
            for (int rs = 0; rs < 2; ++rs) {
                const int ar = rs*16 + (lane & 15);
                const int off = (ar*512 + kb*64 + (lane >> 4)*16) ^ ((ar & 7) << 4);
                ahi[rs] = *(const bf16x8*)((char*)hhi + off);
                alo[rs] = *(const bf16x8*)((char*)hlo + off);
            }
            #pragma unroll
            for (int n = 0; n < 4; ++n) {
                #pragma unroll
                for (int rs = 0; rs < 2; ++rs) {
                    acc[rs][n] = __builtin_amdgcn_mfma_f32_16x16x32_bf16(ahi[rs], wh[n], acc[rs][n], 0, 0, 0);
                    acc[rs][n] = __builtin_amdgcn_mfma_f32_16x16x32_bf16(ahi[rs], wl[n], acc[rs][n], 0, 0, 0);
                    acc[rs][n] = __builtin_amdgcn_mfma_f32_16x16x32_bf16(alo[rs], wh[n], acc[rs][n], 0, 0, 0);
                }
            }
        }
        __syncthreads();   // all reads of h done before overwrite
        if (l < 2) {
            #pragma unroll
            for (int n = 0; n < 4; ++n) {
                const int col = (w4 + n)*16 + (lane & 15);
                const float bias = gb[(l+1)*256 + col];
                #pragma unroll
                for (int rs = 0; rs < 2; ++rs) {
                    #pragma unroll
                    for (int r = 0; r < 4; ++r) {
                        const int row = rs*16 + 4*(lane >> 4) + r;
                        const float v = fmaxf(acc[rs][n][r] + bias, 0.f);
                        const unsigned short hv = f2bf(v);
                        const float lv = v - bf2f(hv);
                        const int byte = (row*512 + col*2) ^ ((row & 7) << 4);
                        *(unsigned short*)((char*)hhi + byte) = hv;
                        *(unsigned short*)((char*)hlo + byte) = f2bf(lv);
                    }
                }
            }
            __syncthreads();
        } else {
            #pragma unroll
            for (int n = 0; n < 4; ++n) {
                const int col = (w4 + n)*16 + (lane & 15);
                const float bias = gb[3*256 + col];
                float s = 0.f;
                #pragma unroll
                for (int rs = 0; rs < 2; ++rs) {
                    #pragma unroll
                    for (int r = 0; r < 4; ++r) {
                        const int row = rs*16 + 4*(lane >> 4) + r;
                        if (row0 + row < 625) s += fmaxf(acc[rs][n][r] + bias, 0.f);
                    }
                }
                s += __shfl_xor(s, 16);
                s += __shfl_xor(s, 32);
                if (lane < 16) atomicAdd(&xg[b*256 + col], s);
            }
        }
    }
}

// ---------------- fused head — EXACT round-11 ----------------
__global__ __launch_bounds__(256) void k_head(
    const float* __restrict__ XG, const float* __restrict__ fw1T, const float* __restrict__ fb1,
    const float* __restrict__ fc2T, const float* __restrict__ fc2b,
    const float* __restrict__ fc3T, const float* __restrict__ fc3b, float* __restrict__ out)
{
    __shared__ float xa[256], xb[256], ys[128];
    const int b = blockIdx.x, t = threadIdx.x;
    xa[t] = XG[b*256 + t];
    __syncthreads();
    float s = fb1[t];
    #pragma unroll 8
    for (int k = 0; k < 256; ++k) s += xa[k] * fw1T[k*256 + t];
    xb[t] = fmaxf(s, 0.f);
    __syncthreads();
    s = fc2b[t];
    #pragma unroll 8
    for (int k = 0; k < 256; ++k) s += xb[k] * fc2T[k*256 + t];
    xa[t] = fmaxf(s, 0.f);
    __syncthreads();
    if (t < 128) {
        s = fc3b[t];
        #pragma unroll 8
        for (int k = 0; k < 256; ++k) s += xa[k] * fc3T[k*128 + t];
        ys[t] = s;
    }
    __syncthreads();
    if (t < 16) {
        float m = ys[t*8];
        #pragma unroll
        for (int i = 1; i < 8; ++i) m = fmaxf(m, ys[t*8 + i]);
        float e[8], sum = 0.f;
        #pragma unroll
        for (int i = 0; i < 8; ++i) { e[i] = expf(ys[t*8 + i] - m); sum += e[i]; }
        const float inv = 1.f / sum;
        #pragma unroll
        for (int i = 0; i < 8; ++i) out[b*128 + t*8 + i] = fmaxf(e[i]*inv, 0.001f);
    }
}

extern "C" void kernel_launch(void* const* d_in, const int* in_sizes, int n_in,
                              void* d_out, int out_size, void* d_ws, size_t ws_size,
                              hipStream_t stream)
{
    const float* img   = (const float*)d_in[0];
    const float* img2  = (const float*)d_in[1];
    const float* cw1   = (const float*)d_in[2];
    const float* cw234 = (const float*)d_in[3];
    const float* cb    = (const float*)d_in[4];
    const float* bng   = (const float*)d_in[5];
    const float* bnb   = (const float*)d_in[6];
    const float* gw1   = (const float*)d_in[7];
    const float* gw234 = (const float*)d_in[8];
    const float* gb    = (const float*)d_in[9];
    const float* fw1   = (const float*)d_in[10];
    const float* fb1   = (const float*)d_in[11];
    const float* fc2w  = (const float*)d_in[12];
    const float* fc2b  = (const float*)d_in[13];
    const float* fc3w  = (const float*)d_in[14];
    const float* fc3b  = (const float*)d_in[15];

    float* ws = (float*)d_ws;
    float* P0 = ws + OFF_P0;  float* P1 = ws + OFF_P1;   float* SS  = ws + OFF_SS;
    float* SA = ws + OFF_SACC; float* Ub = ws + OFF_U;   float* Vb  = ws + OFF_V;
    float* Qb = ws + OFF_Q;
    unsigned short* WP = (unsigned short*)(ws + OFF_WP);
    float* W1UV = ws + OFF_W1UV; float* W1Q = ws + OFF_W1Q;
    float* FW1T = ws + OFF_FW1T; float* FC2T = ws + OFF_FC2T; float* FC3T = ws + OFF_FC3T;
    float* XG = ws + OFF_XG;
    float* out = (float*)d_out;

    hipLaunchKernelGGL(k_prep, dim3(1599), dim3(256), 0, stream, gw1, gw234, fw1, fc2w, fc3w, ws);

    // conv1: LDS-tiled, 128 imgs x 5 row-tiles
    hipLaunchKernelGGL(k_convF, dim3(640), dim3(256), 0, stream, img, img2, cw1, cb, P0);
    hipLaunchKernelGGL(k_stats_part, dim3(384), dim3(256), 0, stream, P0, SA, 1600);
    hipLaunchKernelGGL(k_stats_fin,  dim3(1),   dim3(64),  0, stream, SA, bng, bnb, SS, 1600);
    // conv2: 40x40 -> 20x20; TH=4, nty=5
    hipLaunchKernelGGL(k_convL, dim3(640), dim3(256), 0, stream,
                       P0, SS, cw234, cb + 24, P1, 40, 40, 20, 20, 4, 5);
    hipLaunchKernelGGL(k_stats, dim3(48), dim3(256), 0, stream, P1, bng+24, bnb+24, SS+96, 400);
    // conv3: 20x20 -> 10x10; TH=5, nty=2
    hipLaunchKernelGGL(k_convL, dim3(256), dim3(256), 0, stream,
                       P1, SS + 96, cw234 + 5184, cb + 48, P0, 20, 20, 10, 10, 5, 2);
    hipLaunchKernelGGL(k_stats, dim3(48), dim3(256), 0, stream, P0, bng+48, bnb+48, SS+192, 100);
    // conv4: 10x10 -> 5x5; TH=5, nty=1
    hipLaunchKernelGGL(k_convL, dim3(128), dim3(256), 0, stream,
                       P0, SS + 192, cw234 + 10368, cb + 72, P1, 10, 10, 5, 5, 5, 1);
    hipLaunchKernelGGL(k_stats, dim3(48), dim3(256), 0, stream, P1, bng+72, bnb+72, SS+288, 25);

    // fused U/V + Q (blocks 0-1599 = uv, 1600-1663 = q)
    hipLaunchKernelGGL(k_uvq, dim3(1664), dim3(256), 0, stream,
                       P1, SS+288, W1UV, W1Q, gb, Ub, Vb, Qb);

    hipLaunchKernelGGL(k_gmlp, dim3(1280), dim3(256), 0, stream, Ub, Vb, Qb, WP, gb, XG);

    hipLaunchKernelGGL(k_head, dim3(64), dim3(256), 0, stream,
                       XG, FW1T, fb1, FC2T, fc2b, FC3T, fc3b, out);
}